// Round 6
// baseline (3568.652 us; speedup 1.0000x reference)
//
#include <hip/hip_runtime.h>
#include <hip/hip_bf16.h>
#include <math.h>

typedef __hip_bfloat16 bf16;
typedef unsigned short ushort_t;
typedef __attribute__((ext_vector_type(8))) short short8;
typedef __attribute__((ext_vector_type(4))) float f32x4;

constexpr int NB = 128;      // batch
constexpr int NT = 256;      // time
constexpr int HCAT = 1024;   // 512+256+256

__device__ inline float bf2f(ushort_t u) {
  union { unsigned i; float f; } x; x.i = (unsigned)u << 16; return x.f;
}
__device__ inline ushort_t f2bf(float f) {
  bf16 b = __float2bfloat16(f);
  return *reinterpret_cast<ushort_t*>(&b);
}

// LLC-coherent (agent-scope, relaxed => no cache-maintenance) 16B h-frag load
__device__ inline short8 ldh16(const ushort_t* p) {
  union { unsigned long long u[2]; short8 v; } x;
  unsigned long long* q = const_cast<unsigned long long*>(
      reinterpret_cast<const unsigned long long*>(p));
  x.u[0] = __hip_atomic_load(q,     __ATOMIC_RELAXED, __HIP_MEMORY_SCOPE_AGENT);
  x.u[1] = __hip_atomic_load(q + 1, __ATOMIC_RELAXED, __HIP_MEMORY_SCOPE_AGENT);
  return x.v;
}

// ---------------------------------------------------------------------------
// gx = x @ W_ih^T + b_ih + b_hh   (fp32 compute, bf16 store), time-chunked.
// ---------------------------------------------------------------------------
__global__ __launch_bounds__(256) void k_gx(
    const float* __restrict__ x, const float* __restrict__ W,
    const float* __restrict__ bih, const float* __restrict__ bhh,
    bf16* __restrict__ gx, int d, int G, int t0, int tcShift)
{
  __shared__ float xs[32][68];
  __shared__ float ws_[32][68];
  const int bt0 = blockIdx.x * 64;
  const int r0  = blockIdx.y * 64;
  const int tid = threadIdx.x;
  const int tx = tid & 15;   // gate-row micro
  const int ty = tid >> 4;   // bt micro
  const int tcMask = (1 << tcShift) - 1;
  float acc[4][4];
#pragma unroll
  for (int p = 0; p < 4; ++p)
#pragma unroll
    for (int q = 0; q < 4; ++q) acc[p][q] = 0.f;

  for (int k0 = 0; k0 < d; k0 += 32) {
#pragma unroll
    for (int it = 0; it < 8; ++it) {
      int idx = tid + it * 256;
      int k = idx & 31, i = idx >> 5;
      int kk = k0 + k;
      int row = bt0 + i;
      int b = row >> tcShift, tl = row & tcMask;
      xs[k][i]  = (kk < d) ? x[((size_t)b * NT + t0 + tl) * d + kk] : 0.f;
      ws_[k][i] = (kk < d) ? W[(size_t)(r0 + i) * d + kk] : 0.f;
    }
    __syncthreads();
#pragma unroll 8
    for (int k = 0; k < 32; ++k) {
      float a[4], b[4];
#pragma unroll
      for (int p = 0; p < 4; ++p) a[p] = xs[k][ty * 4 + p];
#pragma unroll
      for (int q = 0; q < 4; ++q) b[q] = ws_[k][tx * 4 + q];
#pragma unroll
      for (int p = 0; p < 4; ++p)
#pragma unroll
        for (int q = 0; q < 4; ++q) acc[p][q] += a[p] * b[q];
    }
    __syncthreads();
  }
#pragma unroll
  for (int p = 0; p < 4; ++p) {
    int bt = bt0 + ty * 4 + p;
#pragma unroll
    for (int q = 0; q < 4; ++q) {
      int r = r0 + tx * 4 + q;
      float v = acc[p][q] + bih[r] + bhh[r];
      gx[(size_t)bt * G + r] = __float2bfloat16(v);
    }
  }
}

// ---------------------------------------------------------------------------
// fc1: Z = relu(A @ W1^T + b1)    A bf16 [rows,1024] (chunk), W fp32 [256,1024]
// ---------------------------------------------------------------------------
__global__ __launch_bounds__(256) void k_fc1(
    const bf16* __restrict__ A, const float* __restrict__ W,
    const float* __restrict__ bias, float* __restrict__ Z)
{
  __shared__ float xs[32][68];
  __shared__ float ws_[32][68];
  const int bt0 = blockIdx.x * 64;
  const int r0  = blockIdx.y * 64;
  const int tid = threadIdx.x;
  const int tx = tid & 15;
  const int ty = tid >> 4;
  float acc[4][4];
#pragma unroll
  for (int p = 0; p < 4; ++p)
#pragma unroll
    for (int q = 0; q < 4; ++q) acc[p][q] = 0.f;

  for (int k0 = 0; k0 < 1024; k0 += 32) {
#pragma unroll
    for (int it = 0; it < 8; ++it) {
      int idx = tid + it * 256;
      int k = idx & 31, i = idx >> 5;
      xs[k][i]  = __bfloat162float(A[(size_t)(bt0 + i) * 1024 + k0 + k]);
      ws_[k][i] = W[(size_t)(r0 + i) * 1024 + k0 + k];
    }
    __syncthreads();
#pragma unroll 8
    for (int k = 0; k < 32; ++k) {
      float a[4], b[4];
#pragma unroll
      for (int p = 0; p < 4; ++p) a[p] = xs[k][ty * 4 + p];
#pragma unroll
      for (int q = 0; q < 4; ++q) b[q] = ws_[k][tx * 4 + q];
#pragma unroll
      for (int p = 0; p < 4; ++p)
#pragma unroll
        for (int q = 0; q < 4; ++q) acc[p][q] += a[p] * b[q];
    }
    __syncthreads();
  }
#pragma unroll
  for (int p = 0; p < 4; ++p) {
    int bt = bt0 + ty * 4 + p;
#pragma unroll
    for (int q = 0; q < 4; ++q) {
      int r = r0 + tx * 4 + q;
      float v = acc[p][q] + bias[r];
      Z[(size_t)bt * 256 + r] = fmaxf(v, 0.f);
    }
  }
}

// ---------------------------------------------------------------------------
// fc2 + log_softmax: one wave per chunk row; map chunk row -> global (b,t)
// ---------------------------------------------------------------------------
__global__ __launch_bounds__(256) void k_fc2(
    const float* __restrict__ Z, const float* __restrict__ W2,
    const float* __restrict__ b2, float* __restrict__ out, int t0, int tcShift)
{
  const int wave = threadIdx.x >> 6;
  const int lane = threadIdx.x & 63;
  const int bt = blockIdx.x * 4 + wave;
  const float* z = Z + (size_t)bt * 256;
  float zv[4];
#pragma unroll
  for (int j = 0; j < 4; ++j) zv[j] = z[lane + 64 * j];
  float lg[7];
#pragma unroll
  for (int o = 0; o < 7; ++o) {
    float a = 0.f;
#pragma unroll
    for (int j = 0; j < 4; ++j) a += zv[j] * W2[o * 256 + lane + 64 * j];
#pragma unroll
    for (int off = 32; off > 0; off >>= 1) a += __shfl_down(a, off, 64);
    lg[o] = a;   // valid on lane 0
  }
  if (lane == 0) {
    const int b = bt >> tcShift;
    const int tl = bt & ((1 << tcShift) - 1);
    float* op = out + ((size_t)b * NT + t0 + tl) * 7;
    float lo[7];
    float m = -1e30f;
#pragma unroll
    for (int o = 0; o < 7; ++o) { lo[o] = lg[o] + b2[o]; m = fmaxf(m, lo[o]); }
    float s = 0.f;
#pragma unroll
    for (int o = 0; o < 7; ++o) s += expf(lo[o] - m);
    float lse = m + logf(s);
#pragma unroll
    for (int o = 0; o < 7; ++o) op[o] = lo[o] - lse;
  }
}

// ---------------------------------------------------------------------------
// Recurrent kernel: register-stationary bf16 weights + MFMA.
// Sync: per-producer FLAG WORDS (64B apart, relaxed atomic stores - zero RMW
// contention; R5's single contended counter line serialized 32 RMWs/step).
// Vectorized poll: lane i of each wave loads flag i -> ONE global_load polls
// all producers; __all(v>=target) detects completion. Waves poll
// independently. h exchange stays relaxed-atomic via LLC (R5-proven).
// ---------------------------------------------------------------------------
template<int HL>
__device__ void lstm_body(const float* __restrict__ Whh,
                          const ushort_t* __restrict__ gx,   // bf16 bits, [NB][TC][4*HL]
                          ushort_t* __restrict__ hbuf,       // bf16 [2][NB][HCAT]
                          float* __restrict__ cbuf,          // fp32 [NB][HCAT]
                          ushort_t* __restrict__ hs,         // bf16 [NB][TC][HCAT]
                          float (*gbuf)[16][17],
                          unsigned* flags, int myblk, int nblk,
                          int g, int u0, int hoff, int t0, int TC)
{
  constexpr int KC = HL / 32;
  const int tid  = threadIdx.x;
  const int lane = tid & 63;
  const int wgate = tid >> 6;        // wave index == gate (i,f,g,o)
  const int n    = lane & 15;        // B: unit within tile / A: batch within group
  const int quad = lane >> 4;

  // ---- load this wave's gate weights once into register B-fragments ----
  short8 wfrag[KC];
  {
    const float* wrow = Whh + ((size_t)wgate * HL + u0 + n) * HL + quad * 8;
#pragma unroll
    for (int kc = 0; kc < KC; ++kc) {
      short8 f;
#pragma unroll
      for (int j = 0; j < 8; ++j) f[j] = (short)f2bf(wrow[kc * 32 + j]);
      wfrag[kc] = f;
    }
  }

  // per-thread cell state mapping for the epilogue
  const int eu = tid & 15;           // unit
  const int eb = tid >> 4;           // batch within group
  const int bb = g * 16 + eb;
  const int hcol = hoff + u0 + eu;
  float c = cbuf[(size_t)bb * HCAT + hcol];

  const int abb = g * 16 + n;        // batch row this lane reads for A-frags

  // poll address for this lane: flag of producer (lane), 16 u32 (64B) apart
  unsigned* myflagp = flags + (lane < nblk ? lane : 0) * 16;

  // gx prefetch: values for step t live in registers across the t-1 barrier
  const ushort_t* gxp = gx + (size_t)bb * TC * (size_t)(4 * HL) + u0 + eu;
  float gxv[4];
#pragma unroll
  for (int q = 0; q < 4; ++q) gxv[q] = bf2f(gxp[(size_t)q * HL]);

  for (int t = 0; t < TC; ++t) {
    // wait until all producers have published h(t). target t0+t; flags start
    // at 0 (h0 zeroed), so step 0 of the first chunk passes immediately.
    const unsigned target = (unsigned)(t0 + t);
    while (true) {
      unsigned v = __hip_atomic_load(myflagp, __ATOMIC_RELAXED, __HIP_MEMORY_SCOPE_AGENT);
      if (__all(v >= target)) break;
      __builtin_amdgcn_s_sleep(1);
    }

    const ushort_t* hrow =
        hbuf + ((size_t)(t & 1) * NB + abb) * HCAT + hoff + quad * 8;
    f32x4 acc = {0.f, 0.f, 0.f, 0.f};
#pragma unroll
    for (int kc = 0; kc < KC; ++kc) {
      short8 a = ldh16(hrow + kc * 32);
      acc = __builtin_amdgcn_mfma_f32_16x16x32_bf16(a, wfrag[kc], acc, 0, 0, 0);
    }
    // D layout: col(unit)=lane&15, row(batch)=quad*4+r
#pragma unroll
    for (int r = 0; r < 4; ++r) gbuf[wgate][quad * 4 + r][n] = acc[r];
    __syncthreads();

    float pi = gbuf[0][eb][eu] + gxv[0];
    float pf = gbuf[1][eb][eu] + gxv[1];
    float pg = gbuf[2][eb][eu] + gxv[2];
    float po = gbuf[3][eb][eu] + gxv[3];
    float si = 1.f / (1.f + expf(-pi));
    float sf = 1.f / (1.f + expf(-pf));
    float so = 1.f / (1.f + expf(-po));
    float tg = tanhf(pg);
    c = sf * c + si * tg;
    float h = so * tanhf(c);
    ushort_t hb = f2bf(h);

    // pair adjacent units' bf16 into one 4B relaxed agent atomic store (LLC)
    unsigned nbv = (unsigned)(ushort_t)__shfl_down((int)hb, 1, 64);
    if ((eu & 1) == 0) {
      unsigned paired = (unsigned)hb | (nbv << 16);
      unsigned* dst = reinterpret_cast<unsigned*>(
          hbuf + ((size_t)((t + 1) & 1) * NB + bb) * HCAT) + (hcol >> 1);
      __hip_atomic_store(dst, paired, __ATOMIC_RELAXED, __HIP_MEMORY_SCOPE_AGENT);
    }
    hs[((size_t)bb * TC + t) * HCAT + hcol] = hb;   // normal store (next kernel)

    // prefetch gx for t+1 before publishing (loads overlap others' polls)
    if (t + 1 < TC) {
#pragma unroll
      for (int q = 0; q < 4; ++q)
        gxv[q] = bf2f(gxp[((size_t)(t + 1) * 4 + q) * (size_t)HL]);
    }

    // drain this block's h stores (compiler emits s_waitcnt vmcnt(0) before
    // s_barrier), then publish our flag for step t+1
    __syncthreads();
    if (tid == 0) {
      __hip_atomic_store(flags + myblk * 16, (unsigned)(t0 + t + 1),
                         __ATOMIC_RELAXED, __HIP_MEMORY_SCOPE_AGENT);
    }
  }
  cbuf[(size_t)bb * HCAT + hcol] = c;
}

__global__ __launch_bounds__(256, 2) void k_lstm(
    const float* __restrict__ Whh0, const float* __restrict__ Whh1,
    const float* __restrict__ Whh2,
    const ushort_t* __restrict__ gx0, const ushort_t* __restrict__ gx1,
    const ushort_t* __restrict__ gx2,
    ushort_t* __restrict__ hbuf, float* __restrict__ cbuf,
    ushort_t* __restrict__ hs,
    unsigned* __restrict__ bar,        // flags: [8 groups][3 layers][32 slots x 16 u32]
    int t0, int TC)
{
  __shared__ float gbuf[4][16][17];
  const int g    = blockIdx.x & 7;
  const int rank = blockIdx.x >> 3;
  if (rank < 32) {
    lstm_body<512>(Whh0, gx0, hbuf, cbuf, hs, gbuf,
                   bar + (g * 3 + 0) * 32 * 16, rank, 32,
                   g, rank * 16, 0, t0, TC);
  } else if (rank < 48) {
    lstm_body<256>(Whh1, gx1, hbuf, cbuf, hs, gbuf,
                   bar + (g * 3 + 1) * 32 * 16, rank - 32, 16,
                   g, (rank - 32) * 16, 512, t0, TC);
  } else {
    lstm_body<256>(Whh2, gx2, hbuf, cbuf, hs, gbuf,
                   bar + (g * 3 + 2) * 32 * 16, rank - 48, 16,
                   g, (rank - 48) * 16, 768, t0, TC);
  }
}

// fallback if workspace is too small: distinctive sentinel
__global__ void k_fill(float* __restrict__ out, int n, float v) {
  int i = blockIdx.x * 256 + threadIdx.x;
  if (i < n) out[i] = v;
}

extern "C" void kernel_launch(void* const* d_in, const int* in_sizes, int n_in,
                              void* d_out, int out_size, void* d_ws, size_t ws_size,
                              hipStream_t stream) {
  (void)in_sizes; (void)n_in;
  const float* x0  = (const float*)d_in[0];
  const float* x1  = (const float*)d_in[1];
  const float* x2  = (const float*)d_in[2];
  const float* Wih0 = (const float*)d_in[3];
  const float* Whh0 = (const float*)d_in[4];
  const float* bih0 = (const float*)d_in[5];
  const float* bhh0 = (const float*)d_in[6];
  const float* Wih1 = (const float*)d_in[7];
  const float* Whh1 = (const float*)d_in[8];
  const float* bih1 = (const float*)d_in[9];
  const float* bhh1 = (const float*)d_in[10];
  const float* Wih2 = (const float*)d_in[11];
  const float* Whh2 = (const float*)d_in[12];
  const float* bih2 = (const float*)d_in[13];
  const float* bhh2 = (const float*)d_in[14];
  const float* W1 = (const float*)d_in[15];
  const float* b1 = (const float*)d_in[16];
  const float* W2 = (const float*)d_in[17];
  const float* b2 = (const float*)d_in[18];
  float* out = (float*)d_out;

  // pick largest even chunk TC that fits in ws
  const int cands[6] = {256, 128, 64, 32, 16, 8};
  int TC = 0;
  for (int ci = 0; ci < 6; ++ci) {
    int tc = cands[ci];
    size_t rows = (size_t)NB * tc;
    size_t o = 0;
    auto al = [&](size_t bytes) { o += (bytes + 255) & ~(size_t)255; };
    al(24 * 32 * 16 * sizeof(unsigned)); // flags
    al((size_t)2 * NB * HCAT * 2);      // hbuf (bf16)
    al((size_t)NB * HCAT * 4);          // cbuf (fp32)
    al(rows * HCAT * 2);                // hs chunk
    al(rows * 256 * 4);                 // z chunk
    al(rows * 2048 * 2);                // gx0 chunk
    al(rows * 1024 * 2);                // gx1 chunk
    al(rows * 1024 * 2);                // gx2 chunk
    if (o <= ws_size) { TC = tc; break; }
  }
  if (TC == 0) {
    k_fill<<<dim3((out_size + 255) / 256), dim3(256), 0, stream>>>(out, out_size, -8888.f);
    return;
  }
  const int tcShift = __builtin_ctz(TC);
  const size_t rows = (size_t)NB * TC;

  char* ws = (char*)d_ws;
  size_t off = 0;
  auto alloc = [&](size_t bytes) -> void* {
    void* p = ws + off;
    off += (bytes + 255) & ~(size_t)255;
    return p;
  };
  unsigned* bar  = (unsigned*)alloc(24 * 32 * 16 * sizeof(unsigned));
  ushort_t* hbuf = (ushort_t*)alloc((size_t)2 * NB * HCAT * 2);
  float* cbuf    = (float*)alloc((size_t)NB * HCAT * 4);
  size_t staticEnd = off;
  ushort_t* hs   = (ushort_t*)alloc(rows * HCAT * 2);
  float* z       = (float*)alloc(rows * 256 * 4);
  bf16* gx0      = (bf16*)alloc(rows * 2048 * 2);
  bf16* gx1      = (bf16*)alloc(rows * 1024 * 2);
  bf16* gx2      = (bf16*)alloc(rows * 1024 * 2);

  // zero flags + hbuf + cbuf (h0 = c0 = 0)
  hipMemsetAsync(ws, 0, staticEnd, stream);

  dim3 blk(256);
  const int rb = (int)(rows / 64);   // row-blocks per chunk
  for (int t0 = 0; t0 < NT; t0 += TC) {
    k_gx<<<dim3(rb, 2048 / 64), blk, 0, stream>>>(x0, Wih0, bih0, bhh0, gx0, 300, 2048, t0, tcShift);
    k_gx<<<dim3(rb, 1024 / 64), blk, 0, stream>>>(x1, Wih1, bih1, bhh1, gx1, 74, 1024, t0, tcShift);
    k_gx<<<dim3(rb, 1024 / 64), blk, 0, stream>>>(x2, Wih2, bih2, bhh2, gx2, 35, 1024, t0, tcShift);

    k_lstm<<<dim3(512), blk, 0, stream>>>(Whh0, Whh1, Whh2,
                                          (const ushort_t*)gx0, (const ushort_t*)gx1,
                                          (const ushort_t*)gx2,
                                          hbuf, cbuf, hs, bar, t0, TC);

    k_fc1<<<dim3(rb, 256 / 64), blk, 0, stream>>>((const bf16*)hs, W1, b1, z);
    k_fc2<<<dim3((int)(rows / 4)), blk, 0, stream>>>(z, W2, b2, out, t0, tcShift);
  }
}

// Round 7
// 2577.399 us; speedup vs baseline: 1.3846x; 1.3846x over previous
//
#include <hip/hip_runtime.h>
#include <hip/hip_bf16.h>
#include <math.h>

typedef __hip_bfloat16 bf16;
typedef unsigned short ushort_t;
typedef unsigned long long ull_t;
typedef __attribute__((ext_vector_type(8))) short short8;
typedef __attribute__((ext_vector_type(4))) float f32x4;

constexpr int NB = 128;      // batch
constexpr int NT = 256;      // time
constexpr int HCAT = 1024;   // 512+256+256

__device__ inline float bf2f(ushort_t u) {
  union { unsigned i; float f; } x; x.i = (unsigned)u << 16; return x.f;
}
__device__ inline ushort_t f2bf(float f) {
  bf16 b = __float2bfloat16(f);
  return *reinterpret_cast<ushort_t*>(&b);
}

// ---------------------------------------------------------------------------
// gx = x @ W_ih^T + b_ih + b_hh   (fp32 compute, bf16 store), time-chunked.
// ---------------------------------------------------------------------------
__global__ __launch_bounds__(256) void k_gx(
    const float* __restrict__ x, const float* __restrict__ W,
    const float* __restrict__ bih, const float* __restrict__ bhh,
    bf16* __restrict__ gx, int d, int G, int t0, int tcShift)
{
  __shared__ float xs[32][68];
  __shared__ float ws_[32][68];
  const int bt0 = blockIdx.x * 64;
  const int r0  = blockIdx.y * 64;
  const int tid = threadIdx.x;
  const int tx = tid & 15;   // gate-row micro
  const int ty = tid >> 4;   // bt micro
  const int tcMask = (1 << tcShift) - 1;
  float acc[4][4];
#pragma unroll
  for (int p = 0; p < 4; ++p)
#pragma unroll
    for (int q = 0; q < 4; ++q) acc[p][q] = 0.f;

  for (int k0 = 0; k0 < d; k0 += 32) {
#pragma unroll
    for (int it = 0; it < 8; ++it) {
      int idx = tid + it * 256;
      int k = idx & 31, i = idx >> 5;
      int kk = k0 + k;
      int row = bt0 + i;
      int b = row >> tcShift, tl = row & tcMask;
      xs[k][i]  = (kk < d) ? x[((size_t)b * NT + t0 + tl) * d + kk] : 0.f;
      ws_[k][i] = (kk < d) ? W[(size_t)(r0 + i) * d + kk] : 0.f;
    }
    __syncthreads();
#pragma unroll 8
    for (int k = 0; k < 32; ++k) {
      float a[4], b[4];
#pragma unroll
      for (int p = 0; p < 4; ++p) a[p] = xs[k][ty * 4 + p];
#pragma unroll
      for (int q = 0; q < 4; ++q) b[q] = ws_[k][tx * 4 + q];
#pragma unroll
      for (int p = 0; p < 4; ++p)
#pragma unroll
        for (int q = 0; q < 4; ++q) acc[p][q] += a[p] * b[q];
    }
    __syncthreads();
  }
#pragma unroll
  for (int p = 0; p < 4; ++p) {
    int bt = bt0 + ty * 4 + p;
#pragma unroll
    for (int q = 0; q < 4; ++q) {
      int r = r0 + tx * 4 + q;
      float v = acc[p][q] + bih[r] + bhh[r];
      gx[(size_t)bt * G + r] = __float2bfloat16(v);
    }
  }
}

// ---------------------------------------------------------------------------
// fc1: Z = relu(A @ W1^T + b1)    A bf16 [rows,1024] (chunk), W fp32 [256,1024]
// ---------------------------------------------------------------------------
__global__ __launch_bounds__(256) void k_fc1(
    const bf16* __restrict__ A, const float* __restrict__ W,
    const float* __restrict__ bias, float* __restrict__ Z)
{
  __shared__ float xs[32][68];
  __shared__ float ws_[32][68];
  const int bt0 = blockIdx.x * 64;
  const int r0  = blockIdx.y * 64;
  const int tid = threadIdx.x;
  const int tx = tid & 15;
  const int ty = tid >> 4;
  float acc[4][4];
#pragma unroll
  for (int p = 0; p < 4; ++p)
#pragma unroll
    for (int q = 0; q < 4; ++q) acc[p][q] = 0.f;

  for (int k0 = 0; k0 < 1024; k0 += 32) {
#pragma unroll
    for (int it = 0; it < 8; ++it) {
      int idx = tid + it * 256;
      int k = idx & 31, i = idx >> 5;
      xs[k][i]  = __bfloat162float(A[(size_t)(bt0 + i) * 1024 + k0 + k]);
      ws_[k][i] = W[(size_t)(r0 + i) * 1024 + k0 + k];
    }
    __syncthreads();
#pragma unroll 8
    for (int k = 0; k < 32; ++k) {
      float a[4], b[4];
#pragma unroll
      for (int p = 0; p < 4; ++p) a[p] = xs[k][ty * 4 + p];
#pragma unroll
      for (int q = 0; q < 4; ++q) b[q] = ws_[k][tx * 4 + q];
#pragma unroll
      for (int p = 0; p < 4; ++p)
#pragma unroll
        for (int q = 0; q < 4; ++q) acc[p][q] += a[p] * b[q];
    }
    __syncthreads();
  }
#pragma unroll
  for (int p = 0; p < 4; ++p) {
    int bt = bt0 + ty * 4 + p;
#pragma unroll
    for (int q = 0; q < 4; ++q) {
      int r = r0 + tx * 4 + q;
      float v = acc[p][q] + bias[r];
      Z[(size_t)bt * 256 + r] = fmaxf(v, 0.f);
    }
  }
}

// ---------------------------------------------------------------------------
// fc2 + log_softmax: one wave per chunk row; map chunk row -> global (b,t)
// ---------------------------------------------------------------------------
__global__ __launch_bounds__(256) void k_fc2(
    const float* __restrict__ Z, const float* __restrict__ W2,
    const float* __restrict__ b2, float* __restrict__ out, int t0, int tcShift)
{
  const int wave = threadIdx.x >> 6;
  const int lane = threadIdx.x & 63;
  const int bt = blockIdx.x * 4 + wave;
  const float* z = Z + (size_t)bt * 256;
  float zv[4];
#pragma unroll
  for (int j = 0; j < 4; ++j) zv[j] = z[lane + 64 * j];
  float lg[7];
#pragma unroll
  for (int o = 0; o < 7; ++o) {
    float a = 0.f;
#pragma unroll
    for (int j = 0; j < 4; ++j) a += zv[j] * W2[o * 256 + lane + 64 * j];
#pragma unroll
    for (int off = 32; off > 0; off >>= 1) a += __shfl_down(a, off, 64);
    lg[o] = a;   // valid on lane 0
  }
  if (lane == 0) {
    const int b = bt >> tcShift;
    const int tl = bt & ((1 << tcShift) - 1);
    float* op = out + ((size_t)b * NT + t0 + tl) * 7;
    float lo[7];
    float m = -1e30f;
#pragma unroll
    for (int o = 0; o < 7; ++o) { lo[o] = lg[o] + b2[o]; m = fmaxf(m, lo[o]); }
    float s = 0.f;
#pragma unroll
    for (int o = 0; o < 7; ++o) s += expf(lo[o] - m);
    float lse = m + logf(s);
#pragma unroll
    for (int o = 0; o < 7; ++o) op[o] = lo[o] - lse;
  }
}

// ---------------------------------------------------------------------------
// Recurrent kernel R7: 32 units/block, h(t) staged into LDS ONCE per block.
// R6 issued ~3.1M agent-atomic ops/step (4 waves x identical A-frag loads x
// 512 blocks) -> LLC atomic-throughput bound (~9us/step). Now: each wave
// loads a quarter of the 16xHL h-tile via 8B relaxed atomics into LDS
// (+8 bf16 row pad, 16B-aligned rows), all waves read A-frags via
// ds_read_b128. 256 blocks (16+8+8 per group x 8 groups), 1 block/CU.
// Weights stay register-stationary (2 N-tiles/wave, 128 VGPR @ HL=512).
// Sync: per-producer flag words + vectorized poll (R6-proven).
// ---------------------------------------------------------------------------
template<int HL>
__device__ void lstm_body(const float* __restrict__ Whh,
                          const ushort_t* __restrict__ gx,   // bf16 bits, [NB][TC][4*HL]
                          ushort_t* __restrict__ hbuf,       // bf16 [2][NB][HCAT]
                          float* __restrict__ cbuf,          // fp32 [NB][HCAT]
                          ushort_t* __restrict__ hs,         // bf16 [NB][TC][HCAT]
                          ushort_t* htile,                   // LDS [16][HL+8]
                          float (*gbuf)[16][34],             // LDS gate tiles
                          unsigned* flags, int myblk, int nblk,
                          int g, int u0, int hoff, int t0, int TC)
{
  constexpr int KC  = HL / 32;
  constexpr int LHP = HL + 8;          // padded LDS row, bf16 units
  const int tid  = threadIdx.x;
  const int lane = tid & 63;
  const int wgate = tid >> 6;          // wave index == gate (i,f,g,o)
  const int n    = lane & 15;
  const int quad = lane >> 4;

  // ---- load this wave's gate weights once into register B-fragments ----
  short8 wfrag[2][KC];
#pragma unroll
  for (int tau = 0; tau < 2; ++tau) {
    const float* wrow = Whh + ((size_t)wgate * HL + u0 + 16 * tau + n) * HL + quad * 8;
#pragma unroll
    for (int kc = 0; kc < KC; ++kc) {
      short8 f;
#pragma unroll
      for (int j = 0; j < 8; ++j) f[j] = (short)f2bf(wrow[kc * 32 + j]);
      wfrag[tau][kc] = f;
    }
  }

  // per-thread epilogue mapping: u = unit 0..31, two batch rows bh, bh+8
  const int u  = tid & 31;
  const int bh = tid >> 5;             // 0..7
  const int bb0 = g * 16 + bh;
  const int bb1 = bb0 + 8;
  const int hcol = hoff + u0 + u;
  float c0 = cbuf[(size_t)bb0 * HCAT + hcol];
  float c1 = cbuf[(size_t)bb1 * HCAT + hcol];

  // staging coords: wave w loads batch rows 4w..4w+3 of the group's h tile
  const int srow = wgate * 4 + (lane >> 4);   // 0..15
  const int scol = lane & 15;

  unsigned* myflagp = flags + (lane < nblk ? lane : 0) * 16;

  // gx prefetch registers
  const size_t G4 = (size_t)(4 * HL);
  float gxv0[4], gxv1[4];
#pragma unroll
  for (int q = 0; q < 4; ++q) {
    gxv0[q] = bf2f(gx[((size_t)bb0 * TC) * G4 + (size_t)q * HL + u0 + u]);
    gxv1[q] = bf2f(gx[((size_t)bb1 * TC) * G4 + (size_t)q * HL + u0 + u]);
  }

  for (int t = 0; t < TC; ++t) {
    // wait until all producers of this (group,layer) published h(t)
    const unsigned target = (unsigned)(t0 + t);
    while (true) {
      unsigned v = __hip_atomic_load(myflagp, __ATOMIC_RELAXED, __HIP_MEMORY_SCOPE_AGENT);
      if (__all(v >= target)) break;
      __builtin_amdgcn_s_sleep(1);
    }

    // ---- stage h(t) into LDS (once per block; 8B relaxed agent atomics) ----
    {
      const ushort_t* src =
          hbuf + ((size_t)(t & 1) * NB + g * 16 + srow) * HCAT + hoff;
#pragma unroll
      for (int it = 0; it < HL / 64; ++it) {
        int col = scol * 4 + it * 64;          // bf16 column
        ull_t v = __hip_atomic_load(
            reinterpret_cast<const ull_t*>(src + col),
            __ATOMIC_RELAXED, __HIP_MEMORY_SCOPE_AGENT);
        *reinterpret_cast<ull_t*>(htile + srow * LHP + col) = v;
      }
    }
    __syncthreads();

    // ---- MFMA: D[16 batch][32 units] via 2 N-tiles, A from LDS ----
    f32x4 acc0 = {0.f, 0.f, 0.f, 0.f};
    f32x4 acc1 = {0.f, 0.f, 0.f, 0.f};
#pragma unroll
    for (int kc = 0; kc < KC; ++kc) {
      short8 a = *reinterpret_cast<const short8*>(htile + n * LHP + quad * 8 + kc * 32);
      acc0 = __builtin_amdgcn_mfma_f32_16x16x32_bf16(a, wfrag[0][kc], acc0, 0, 0, 0);
      acc1 = __builtin_amdgcn_mfma_f32_16x16x32_bf16(a, wfrag[1][kc], acc1, 0, 0, 0);
    }
#pragma unroll
    for (int r = 0; r < 4; ++r) {
      gbuf[wgate][quad * 4 + r][n]      = acc0[r];
      gbuf[wgate][quad * 4 + r][16 + n] = acc1[r];
    }
    __syncthreads();

    // ---- epilogue: 2 cells per thread (batch bh and bh+8, unit u) ----
    float pi0 = gbuf[0][bh][u] + gxv0[0];
    float pf0 = gbuf[1][bh][u] + gxv0[1];
    float pg0 = gbuf[2][bh][u] + gxv0[2];
    float po0 = gbuf[3][bh][u] + gxv0[3];
    float pi1 = gbuf[0][bh + 8][u] + gxv1[0];
    float pf1 = gbuf[1][bh + 8][u] + gxv1[1];
    float pg1 = gbuf[2][bh + 8][u] + gxv1[2];
    float po1 = gbuf[3][bh + 8][u] + gxv1[3];

    float si0 = 1.f / (1.f + expf(-pi0));
    float sf0 = 1.f / (1.f + expf(-pf0));
    float so0 = 1.f / (1.f + expf(-po0));
    float tg0 = tanhf(pg0);
    c0 = sf0 * c0 + si0 * tg0;
    float h0 = so0 * tanhf(c0);
    float si1 = 1.f / (1.f + expf(-pi1));
    float sf1 = 1.f / (1.f + expf(-pf1));
    float so1 = 1.f / (1.f + expf(-po1));
    float tg1 = tanhf(pg1);
    c1 = sf1 * c1 + si1 * tg1;
    float h1 = so1 * tanhf(c1);

    ushort_t hb0 = f2bf(h0), hb1 = f2bf(h1);
    unsigned nb0 = (unsigned)(ushort_t)__shfl_down((int)hb0, 1, 64);
    unsigned nb1 = (unsigned)(ushort_t)__shfl_down((int)hb1, 1, 64);
    if ((u & 1) == 0) {
      ushort_t* nxt = hbuf + (size_t)((t + 1) & 1) * NB * HCAT;
      unsigned* d0 = reinterpret_cast<unsigned*>(nxt + (size_t)bb0 * HCAT) + (hcol >> 1);
      unsigned* d1 = reinterpret_cast<unsigned*>(nxt + (size_t)bb1 * HCAT) + (hcol >> 1);
      __hip_atomic_store(d0, (unsigned)hb0 | (nb0 << 16), __ATOMIC_RELAXED, __HIP_MEMORY_SCOPE_AGENT);
      __hip_atomic_store(d1, (unsigned)hb1 | (nb1 << 16), __ATOMIC_RELAXED, __HIP_MEMORY_SCOPE_AGENT);
    }
    hs[((size_t)bb0 * TC + t) * HCAT + hcol] = hb0;   // normal stores (next kernel)
    hs[((size_t)bb1 * TC + t) * HCAT + hcol] = hb1;

    // prefetch gx(t+1) before publishing (overlaps others' polls)
    if (t + 1 < TC) {
#pragma unroll
      for (int q = 0; q < 4; ++q) {
        gxv0[q] = bf2f(gx[((size_t)bb0 * TC + t + 1) * G4 + (size_t)q * HL + u0 + u]);
        gxv1[q] = bf2f(gx[((size_t)bb1 * TC + t + 1) * G4 + (size_t)q * HL + u0 + u]);
      }
    }

    // drain h stores (compiler emits s_waitcnt vmcnt(0) before s_barrier),
    // then publish our flag for step t+1
    __syncthreads();
    if (tid == 0) {
      __hip_atomic_store(flags + myblk * 16, (unsigned)(t0 + t + 1),
                         __ATOMIC_RELAXED, __HIP_MEMORY_SCOPE_AGENT);
    }
  }
  cbuf[(size_t)bb0 * HCAT + hcol] = c0;
  cbuf[(size_t)bb1 * HCAT + hcol] = c1;
}

__global__ __launch_bounds__(256, 1) void k_lstm(
    const float* __restrict__ Whh0, const float* __restrict__ Whh1,
    const float* __restrict__ Whh2,
    const ushort_t* __restrict__ gx0, const ushort_t* __restrict__ gx1,
    const ushort_t* __restrict__ gx2,
    ushort_t* __restrict__ hbuf, float* __restrict__ cbuf,
    ushort_t* __restrict__ hs,
    unsigned* __restrict__ bar,        // flags: [8 groups][3 layers][32 slots x 16 u32]
    int t0, int TC)
{
  __shared__ ushort_t htile[16 * 520];     // max HL=512: 16 x (512+8)
  __shared__ float gbuf[4][16][34];
  const int g    = blockIdx.x & 7;
  const int rank = blockIdx.x >> 3;        // 0..31
  if (rank < 16) {
    lstm_body<512>(Whh0, gx0, hbuf, cbuf, hs, htile, gbuf,
                   bar + (g * 3 + 0) * 32 * 16, rank, 16,
                   g, rank * 32, 0, t0, TC);
  } else if (rank < 24) {
    lstm_body<256>(Whh1, gx1, hbuf, cbuf, hs, htile, gbuf,
                   bar + (g * 3 + 1) * 32 * 16, rank - 16, 8,
                   g, (rank - 16) * 32, 512, t0, TC);
  } else {
    lstm_body<256>(Whh2, gx2, hbuf, cbuf, hs, htile, gbuf,
                   bar + (g * 3 + 2) * 32 * 16, rank - 24, 8,
                   g, (rank - 24) * 32, 768, t0, TC);
  }
}

// fallback if workspace is too small: distinctive sentinel
__global__ void k_fill(float* __restrict__ out, int n, float v) {
  int i = blockIdx.x * 256 + threadIdx.x;
  if (i < n) out[i] = v;
}

extern "C" void kernel_launch(void* const* d_in, const int* in_sizes, int n_in,
                              void* d_out, int out_size, void* d_ws, size_t ws_size,
                              hipStream_t stream) {
  (void)in_sizes; (void)n_in;
  const float* x0  = (const float*)d_in[0];
  const float* x1  = (const float*)d_in[1];
  const float* x2  = (const float*)d_in[2];
  const float* Wih0 = (const float*)d_in[3];
  const float* Whh0 = (const float*)d_in[4];
  const float* bih0 = (const float*)d_in[5];
  const float* bhh0 = (const float*)d_in[6];
  const float* Wih1 = (const float*)d_in[7];
  const float* Whh1 = (const float*)d_in[8];
  const float* bih1 = (const float*)d_in[9];
  const float* bhh1 = (const float*)d_in[10];
  const float* Wih2 = (const float*)d_in[11];
  const float* Whh2 = (const float*)d_in[12];
  const float* bih2 = (const float*)d_in[13];
  const float* bhh2 = (const float*)d_in[14];
  const float* W1 = (const float*)d_in[15];
  const float* b1 = (const float*)d_in[16];
  const float* W2 = (const float*)d_in[17];
  const float* b2 = (const float*)d_in[18];
  float* out = (float*)d_out;

  // pick largest even chunk TC that fits in ws
  const int cands[6] = {256, 128, 64, 32, 16, 8};
  int TC = 0;
  for (int ci = 0; ci < 6; ++ci) {
    int tc = cands[ci];
    size_t rows = (size_t)NB * tc;
    size_t o = 0;
    auto al = [&](size_t bytes) { o += (bytes + 255) & ~(size_t)255; };
    al(24 * 32 * 16 * sizeof(unsigned)); // flags
    al((size_t)2 * NB * HCAT * 2);      // hbuf (bf16)
    al((size_t)NB * HCAT * 4);          // cbuf (fp32)
    al(rows * HCAT * 2);                // hs chunk
    al(rows * 256 * 4);                 // z chunk
    al(rows * 2048 * 2);                // gx0 chunk
    al(rows * 1024 * 2);                // gx1 chunk
    al(rows * 1024 * 2);                // gx2 chunk
    if (o <= ws_size) { TC = tc; break; }
  }
  if (TC == 0) {
    k_fill<<<dim3((out_size + 255) / 256), dim3(256), 0, stream>>>(out, out_size, -8888.f);
    return;
  }
  const int tcShift = __builtin_ctz(TC);
  const size_t rows = (size_t)NB * TC;

  char* ws = (char*)d_ws;
  size_t off = 0;
  auto alloc = [&](size_t bytes) -> void* {
    void* p = ws + off;
    off += (bytes + 255) & ~(size_t)255;
    return p;
  };
  unsigned* bar  = (unsigned*)alloc(24 * 32 * 16 * sizeof(unsigned));
  ushort_t* hbuf = (ushort_t*)alloc((size_t)2 * NB * HCAT * 2);
  float* cbuf    = (float*)alloc((size_t)NB * HCAT * 4);
  size_t staticEnd = off;
  ushort_t* hs   = (ushort_t*)alloc(rows * HCAT * 2);
  float* z       = (float*)alloc(rows * 256 * 4);
  bf16* gx0      = (bf16*)alloc(rows * 2048 * 2);
  bf16* gx1      = (bf16*)alloc(rows * 1024 * 2);
  bf16* gx2      = (bf16*)alloc(rows * 1024 * 2);

  // zero flags + hbuf + cbuf (h0 = c0 = 0)
  hipMemsetAsync(ws, 0, staticEnd, stream);

  dim3 blk(256);
  const int rb = (int)(rows / 64);   // row-blocks per chunk
  for (int t0 = 0; t0 < NT; t0 += TC) {
    k_gx<<<dim3(rb, 2048 / 64), blk, 0, stream>>>(x0, Wih0, bih0, bhh0, gx0, 300, 2048, t0, tcShift);
    k_gx<<<dim3(rb, 1024 / 64), blk, 0, stream>>>(x1, Wih1, bih1, bhh1, gx1, 74, 1024, t0, tcShift);
    k_gx<<<dim3(rb, 1024 / 64), blk, 0, stream>>>(x2, Wih2, bih2, bhh2, gx2, 35, 1024, t0, tcShift);

    k_lstm<<<dim3(256), blk, 0, stream>>>(Whh0, Whh1, Whh2,
                                          (const ushort_t*)gx0, (const ushort_t*)gx1,
                                          (const ushort_t*)gx2,
                                          hbuf, cbuf, hs, bar, t0, TC);

    k_fc1<<<dim3(rb, 256 / 64), blk, 0, stream>>>((const bf16*)hs, W1, b1, z);
    k_fc2<<<dim3((int)(rows / 4)), blk, 0, stream>>>(z, W2, b2, out, t0, tcShift);
  }
}

// Round 8
// 2546.982 us; speedup vs baseline: 1.4011x; 1.0119x over previous
//
#include <hip/hip_runtime.h>
#include <hip/hip_bf16.h>
#include <math.h>

typedef __hip_bfloat16 bf16;
typedef unsigned short ushort_t;
typedef unsigned long long ull_t;
typedef __attribute__((ext_vector_type(8))) short short8;
typedef __attribute__((ext_vector_type(4))) float f32x4;

constexpr int NB = 128;      // batch
constexpr int NT = 256;      // time
constexpr int HCAT = 1024;   // 512+256+256

__device__ inline float bf2f(ushort_t u) {
  union { unsigned i; float f; } x; x.i = (unsigned)u << 16; return x.f;
}
__device__ inline ushort_t f2bf(float f) {
  bf16 b = __float2bfloat16(f);
  return *reinterpret_cast<ushort_t*>(&b);
}

// ---------------------------------------------------------------------------
// gx = x @ W_ih^T + b_ih + b_hh  -- MFMA version (bf16 inputs, fp32 acc).
// 64 rows x 64 gate-cols per block; wave w = col-tile w, 4 row-tiles each.
// x/W staged to LDS as bf16 (converted in flight); K-chunk 32.
// ---------------------------------------------------------------------------
__global__ __launch_bounds__(256) void k_gx_mfma(
    const float* __restrict__ x, const float* __restrict__ W,
    const float* __restrict__ bih, const float* __restrict__ bhh,
    ushort_t* __restrict__ gx, int d, int G, int t0, int tcShift)
{
  __shared__ ushort_t xs[64][40];
  __shared__ ushort_t wsm[64][40];
  const int bt0 = blockIdx.x * 64;
  const int r0  = blockIdx.y * 64;
  const int tid = threadIdx.x;
  const int lane = tid & 63;
  const int w    = tid >> 6;
  const int n    = lane & 15;
  const int quad = lane >> 4;
  const int tcMask = (1 << tcShift) - 1;

  const int si = tid >> 2;            // staging row 0..63
  const int sk = (tid & 3) * 8;       // k offset within chunk
  const int brow = bt0 + si;
  const int bsi = brow >> tcShift, tli = brow & tcMask;
  const float* xrow = x + ((size_t)bsi * NT + t0 + tli) * d;
  const float* wrow = W + (size_t)(r0 + si) * d;

  f32x4 acc[4] = {{0,0,0,0},{0,0,0,0},{0,0,0,0},{0,0,0,0}};
  for (int k0 = 0; k0 < d; k0 += 32) {
    ushort_t tx[8], tw[8];
#pragma unroll
    for (int j = 0; j < 8; ++j) {
      int kk = k0 + sk + j;
      bool ok = kk < d;
      tx[j] = ok ? f2bf(xrow[kk]) : (ushort_t)0;
      tw[j] = ok ? f2bf(wrow[kk]) : (ushort_t)0;
    }
    __syncthreads();   // previous chunk fully consumed
    *reinterpret_cast<short8*>(&xs[si][sk])  = *reinterpret_cast<short8*>(tx);
    *reinterpret_cast<short8*>(&wsm[si][sk]) = *reinterpret_cast<short8*>(tw);
    __syncthreads();
#pragma unroll
    for (int mt = 0; mt < 4; ++mt) {
      short8 a = *reinterpret_cast<const short8*>(&xs[mt * 16 + n][quad * 8]);
      short8 b = *reinterpret_cast<const short8*>(&wsm[w * 16 + n][quad * 8]);
      acc[mt] = __builtin_amdgcn_mfma_f32_16x16x32_bf16(a, b, acc[mt], 0, 0, 0);
    }
  }
  const int col = r0 + w * 16 + n;
  const float bias = bih[col] + bhh[col];
#pragma unroll
  for (int mt = 0; mt < 4; ++mt)
#pragma unroll
    for (int r = 0; r < 4; ++r) {
      int row = bt0 + mt * 16 + quad * 4 + r;
      gx[(size_t)row * G + col] = f2bf(acc[mt][r] + bias);
    }
}

// ---------------------------------------------------------------------------
// fc1: Z = relu(A @ W1^T + b1) -- MFMA version. A bf16 [rows][1024].
// ---------------------------------------------------------------------------
__global__ __launch_bounds__(256) void k_fc1_mfma(
    const ushort_t* __restrict__ A, const float* __restrict__ W,
    const float* __restrict__ bias, float* __restrict__ Z)
{
  __shared__ ushort_t xs[64][40];
  __shared__ ushort_t wsm[64][40];
  const int bt0 = blockIdx.x * 64;
  const int r0  = blockIdx.y * 64;
  const int tid = threadIdx.x;
  const int lane = tid & 63;
  const int w    = tid >> 6;
  const int n    = lane & 15;
  const int quad = lane >> 4;

  const int si = tid >> 2;
  const int sk = (tid & 3) * 8;
  const ushort_t* arow = A + (size_t)(bt0 + si) * 1024;
  const float* wrow = W + (size_t)(r0 + si) * 1024;

  f32x4 acc[4] = {{0,0,0,0},{0,0,0,0},{0,0,0,0},{0,0,0,0}};
  for (int k0 = 0; k0 < 1024; k0 += 32) {
    short8 ta = *reinterpret_cast<const short8*>(arow + k0 + sk);
    ushort_t tw[8];
#pragma unroll
    for (int j = 0; j < 8; ++j) tw[j] = f2bf(wrow[k0 + sk + j]);
    __syncthreads();
    *reinterpret_cast<short8*>(&xs[si][sk])  = ta;
    *reinterpret_cast<short8*>(&wsm[si][sk]) = *reinterpret_cast<short8*>(tw);
    __syncthreads();
#pragma unroll
    for (int mt = 0; mt < 4; ++mt) {
      short8 a = *reinterpret_cast<const short8*>(&xs[mt * 16 + n][quad * 8]);
      short8 b = *reinterpret_cast<const short8*>(&wsm[w * 16 + n][quad * 8]);
      acc[mt] = __builtin_amdgcn_mfma_f32_16x16x32_bf16(a, b, acc[mt], 0, 0, 0);
    }
  }
  const int col = r0 + w * 16 + n;
  const float b = bias[col];
#pragma unroll
  for (int mt = 0; mt < 4; ++mt)
#pragma unroll
    for (int r = 0; r < 4; ++r) {
      int row = bt0 + mt * 16 + quad * 4 + r;
      Z[(size_t)row * 256 + col] = fmaxf(acc[mt][r] + b, 0.f);
    }
}

// ---------------------------------------------------------------------------
// fc2 + log_softmax: one wave per chunk row; map chunk row -> global (b,t)
// ---------------------------------------------------------------------------
__global__ __launch_bounds__(256) void k_fc2(
    const float* __restrict__ Z, const float* __restrict__ W2,
    const float* __restrict__ b2, float* __restrict__ out, int t0, int tcShift)
{
  const int wave = threadIdx.x >> 6;
  const int lane = threadIdx.x & 63;
  const int bt = blockIdx.x * 4 + wave;
  const float* z = Z + (size_t)bt * 256;
  float zv[4];
#pragma unroll
  for (int j = 0; j < 4; ++j) zv[j] = z[lane + 64 * j];
  float lg[7];
#pragma unroll
  for (int o = 0; o < 7; ++o) {
    float a = 0.f;
#pragma unroll
    for (int j = 0; j < 4; ++j) a += zv[j] * W2[o * 256 + lane + 64 * j];
#pragma unroll
    for (int off = 32; off > 0; off >>= 1) a += __shfl_down(a, off, 64);
    lg[o] = a;   // valid on lane 0
  }
  if (lane == 0) {
    const int b = bt >> tcShift;
    const int tl = bt & ((1 << tcShift) - 1);
    float* op = out + ((size_t)b * NT + t0 + tl) * 7;
    float lo[7];
    float m = -1e30f;
#pragma unroll
    for (int o = 0; o < 7; ++o) { lo[o] = lg[o] + b2[o]; m = fmaxf(m, lo[o]); }
    float s = 0.f;
#pragma unroll
    for (int o = 0; o < 7; ++o) s += expf(lo[o] - m);
    float lse = m + logf(s);
#pragma unroll
    for (int o = 0; o < 7; ++o) op[o] = lo[o] - lse;
  }
}

// ---------------------------------------------------------------------------
// Recurrent kernel R8: as R7 (32 units/block, LDS-staged h, flag sync) with
// the publish path shortened: only the h atomic stores drain before the flag
// store; hs stores and gx(t+1) prefetch issue AFTER the flag publish and
// complete during the next poll (R7 drained them on the critical path).
// ---------------------------------------------------------------------------
template<int HL>
__device__ void lstm_body(const float* __restrict__ Whh,
                          const ushort_t* __restrict__ gx,   // bf16 bits, [NB][TC][4*HL]
                          ushort_t* __restrict__ hbuf,       // bf16 [2][NB][HCAT]
                          float* __restrict__ cbuf,          // fp32 [NB][HCAT]
                          ushort_t* __restrict__ hs,         // bf16 [NB][TC][HCAT]
                          ushort_t* htile,                   // LDS [16][HL+8]
                          float (*gbuf)[16][34],             // LDS gate tiles
                          unsigned* flags, int myblk, int nblk,
                          int g, int u0, int hoff, int t0, int TC)
{
  constexpr int KC  = HL / 32;
  constexpr int LHP = HL + 8;          // padded LDS row, bf16 units
  const int tid  = threadIdx.x;
  const int lane = tid & 63;
  const int wgate = tid >> 6;          // wave index == gate (i,f,g,o)
  const int n    = lane & 15;
  const int quad = lane >> 4;

  // ---- load this wave's gate weights once into register B-fragments ----
  short8 wfrag[2][KC];
#pragma unroll
  for (int tau = 0; tau < 2; ++tau) {
    const float* wrow = Whh + ((size_t)wgate * HL + u0 + 16 * tau + n) * HL + quad * 8;
#pragma unroll
    for (int kc = 0; kc < KC; ++kc) {
      short8 f;
#pragma unroll
      for (int j = 0; j < 8; ++j) f[j] = (short)f2bf(wrow[kc * 32 + j]);
      wfrag[tau][kc] = f;
    }
  }

  // per-thread epilogue mapping: u = unit 0..31, two batch rows bh, bh+8
  const int u  = tid & 31;
  const int bh = tid >> 5;             // 0..7
  const int bb0 = g * 16 + bh;
  const int bb1 = bb0 + 8;
  const int hcol = hoff + u0 + u;
  float c0 = cbuf[(size_t)bb0 * HCAT + hcol];
  float c1 = cbuf[(size_t)bb1 * HCAT + hcol];

  // staging coords: wave w loads batch rows 4w..4w+3 of the group's h tile
  const int srow = wgate * 4 + (lane >> 4);   // 0..15
  const int scol = lane & 15;

  unsigned* myflagp = flags + (lane < nblk ? lane : 0) * 16;

  // gx prefetch registers
  const size_t G4 = (size_t)(4 * HL);
  float gxv0[4], gxv1[4];
#pragma unroll
  for (int q = 0; q < 4; ++q) {
    gxv0[q] = bf2f(gx[((size_t)bb0 * TC) * G4 + (size_t)q * HL + u0 + u]);
    gxv1[q] = bf2f(gx[((size_t)bb1 * TC) * G4 + (size_t)q * HL + u0 + u]);
  }

  for (int t = 0; t < TC; ++t) {
    // wait until all producers of this (group,layer) published h(t)
    const unsigned target = (unsigned)(t0 + t);
    while (true) {
      unsigned v = __hip_atomic_load(myflagp, __ATOMIC_RELAXED, __HIP_MEMORY_SCOPE_AGENT);
      if (__all(v >= target)) break;
      __builtin_amdgcn_s_sleep(1);
    }

    // ---- stage h(t) into LDS (once per block; 8B relaxed agent atomics) ----
    {
      const ushort_t* src =
          hbuf + ((size_t)(t & 1) * NB + g * 16 + srow) * HCAT + hoff;
#pragma unroll
      for (int it = 0; it < HL / 64; ++it) {
        int col = scol * 4 + it * 64;          // bf16 column
        ull_t v = __hip_atomic_load(
            reinterpret_cast<const ull_t*>(src + col),
            __ATOMIC_RELAXED, __HIP_MEMORY_SCOPE_AGENT);
        *reinterpret_cast<ull_t*>(htile + srow * LHP + col) = v;
      }
    }
    __syncthreads();

    // ---- MFMA: D[16 batch][32 units] via 2 N-tiles, A from LDS ----
    f32x4 acc0 = {0.f, 0.f, 0.f, 0.f};
    f32x4 acc1 = {0.f, 0.f, 0.f, 0.f};
#pragma unroll
    for (int kc = 0; kc < KC; ++kc) {
      short8 a = *reinterpret_cast<const short8*>(htile + n * LHP + quad * 8 + kc * 32);
      acc0 = __builtin_amdgcn_mfma_f32_16x16x32_bf16(a, wfrag[0][kc], acc0, 0, 0, 0);
      acc1 = __builtin_amdgcn_mfma_f32_16x16x32_bf16(a, wfrag[1][kc], acc1, 0, 0, 0);
    }
#pragma unroll
    for (int r = 0; r < 4; ++r) {
      gbuf[wgate][quad * 4 + r][n]      = acc0[r];
      gbuf[wgate][quad * 4 + r][16 + n] = acc1[r];
    }
    __syncthreads();

    // ---- epilogue: 2 cells per thread (batch bh and bh+8, unit u) ----
    float pi0 = gbuf[0][bh][u] + gxv0[0];
    float pf0 = gbuf[1][bh][u] + gxv0[1];
    float pg0 = gbuf[2][bh][u] + gxv0[2];
    float po0 = gbuf[3][bh][u] + gxv0[3];
    float pi1 = gbuf[0][bh + 8][u] + gxv1[0];
    float pf1 = gbuf[1][bh + 8][u] + gxv1[1];
    float pg1 = gbuf[2][bh + 8][u] + gxv1[2];
    float po1 = gbuf[3][bh + 8][u] + gxv1[3];

    float si0 = 1.f / (1.f + expf(-pi0));
    float sf0 = 1.f / (1.f + expf(-pf0));
    float so0 = 1.f / (1.f + expf(-po0));
    float tg0 = tanhf(pg0);
    c0 = sf0 * c0 + si0 * tg0;
    float h0 = so0 * tanhf(c0);
    float si1 = 1.f / (1.f + expf(-pi1));
    float sf1 = 1.f / (1.f + expf(-pf1));
    float so1 = 1.f / (1.f + expf(-po1));
    float tg1 = tanhf(pg1);
    c1 = sf1 * c1 + si1 * tg1;
    float h1 = so1 * tanhf(c1);

    ushort_t hb0 = f2bf(h0), hb1 = f2bf(h1);
    unsigned nb0 = (unsigned)(ushort_t)__shfl_down((int)hb0, 1, 64);
    unsigned nb1 = (unsigned)(ushort_t)__shfl_down((int)hb1, 1, 64);
    if ((u & 1) == 0) {
      ushort_t* nxt = hbuf + (size_t)((t + 1) & 1) * NB * HCAT;
      unsigned* d0 = reinterpret_cast<unsigned*>(nxt + (size_t)bb0 * HCAT) + (hcol >> 1);
      unsigned* d1 = reinterpret_cast<unsigned*>(nxt + (size_t)bb1 * HCAT) + (hcol >> 1);
      __hip_atomic_store(d0, (unsigned)hb0 | (nb0 << 16), __ATOMIC_RELAXED, __HIP_MEMORY_SCOPE_AGENT);
      __hip_atomic_store(d1, (unsigned)hb1 | (nb1 << 16), __ATOMIC_RELAXED, __HIP_MEMORY_SCOPE_AGENT);
    }

    // drain ONLY the h stores (all waves wait vmcnt(0) before s_barrier),
    // then publish immediately
    __syncthreads();
    if (tid == 0) {
      __hip_atomic_store(flags + myblk * 16, (unsigned)(t0 + t + 1),
                         __ATOMIC_RELAXED, __HIP_MEMORY_SCOPE_AGENT);
    }

    // off-critical-path work: hs stores (consumed by k_fc1 after kernel end)
    // and gx(t+1) prefetch -- both complete during the next poll
    hs[((size_t)bb0 * TC + t) * HCAT + hcol] = hb0;
    hs[((size_t)bb1 * TC + t) * HCAT + hcol] = hb1;
    if (t + 1 < TC) {
#pragma unroll
      for (int q = 0; q < 4; ++q) {
        gxv0[q] = bf2f(gx[((size_t)bb0 * TC + t + 1) * G4 + (size_t)q * HL + u0 + u]);
        gxv1[q] = bf2f(gx[((size_t)bb1 * TC + t + 1) * G4 + (size_t)q * HL + u0 + u]);
      }
    }
  }
  cbuf[(size_t)bb0 * HCAT + hcol] = c0;
  cbuf[(size_t)bb1 * HCAT + hcol] = c1;
}

__global__ __launch_bounds__(256, 1) void k_lstm(
    const float* __restrict__ Whh0, const float* __restrict__ Whh1,
    const float* __restrict__ Whh2,
    const ushort_t* __restrict__ gx0, const ushort_t* __restrict__ gx1,
    const ushort_t* __restrict__ gx2,
    ushort_t* __restrict__ hbuf, float* __restrict__ cbuf,
    ushort_t* __restrict__ hs,
    unsigned* __restrict__ bar,        // flags: [8 groups][3 layers][32 slots x 16 u32]
    int t0, int TC)
{
  __shared__ ushort_t htile[16 * 520];     // max HL=512: 16 x (512+8)
  __shared__ float gbuf[4][16][34];
  const int g    = blockIdx.x & 7;
  const int rank = blockIdx.x >> 3;        // 0..31
  if (rank < 16) {
    lstm_body<512>(Whh0, gx0, hbuf, cbuf, hs, htile, gbuf,
                   bar + (g * 3 + 0) * 32 * 16, rank, 16,
                   g, rank * 32, 0, t0, TC);
  } else if (rank < 24) {
    lstm_body<256>(Whh1, gx1, hbuf, cbuf, hs, htile, gbuf,
                   bar + (g * 3 + 1) * 32 * 16, rank - 16, 8,
                   g, (rank - 16) * 32, 512, t0, TC);
  } else {
    lstm_body<256>(Whh2, gx2, hbuf, cbuf, hs, htile, gbuf,
                   bar + (g * 3 + 2) * 32 * 16, rank - 24, 8,
                   g, (rank - 24) * 32, 768, t0, TC);
  }
}

// fallback if workspace is too small: distinctive sentinel
__global__ void k_fill(float* __restrict__ out, int n, float v) {
  int i = blockIdx.x * 256 + threadIdx.x;
  if (i < n) out[i] = v;
}

extern "C" void kernel_launch(void* const* d_in, const int* in_sizes, int n_in,
                              void* d_out, int out_size, void* d_ws, size_t ws_size,
                              hipStream_t stream) {
  (void)in_sizes; (void)n_in;
  const float* x0  = (const float*)d_in[0];
  const float* x1  = (const float*)d_in[1];
  const float* x2  = (const float*)d_in[2];
  const float* Wih0 = (const float*)d_in[3];
  const float* Whh0 = (const float*)d_in[4];
  const float* bih0 = (const float*)d_in[5];
  const float* bhh0 = (const float*)d_in[6];
  const float* Wih1 = (const float*)d_in[7];
  const float* Whh1 = (const float*)d_in[8];
  const float* bih1 = (const float*)d_in[9];
  const float* bhh1 = (const float*)d_in[10];
  const float* Wih2 = (const float*)d_in[11];
  const float* Whh2 = (const float*)d_in[12];
  const float* bih2 = (const float*)d_in[13];
  const float* bhh2 = (const float*)d_in[14];
  const float* W1 = (const float*)d_in[15];
  const float* b1 = (const float*)d_in[16];
  const float* W2 = (const float*)d_in[17];
  const float* b2 = (const float*)d_in[18];
  float* out = (float*)d_out;

  // pick largest even chunk TC that fits in ws
  const int cands[6] = {256, 128, 64, 32, 16, 8};
  int TC = 0;
  for (int ci = 0; ci < 6; ++ci) {
    int tc = cands[ci];
    size_t rows = (size_t)NB * tc;
    size_t o = 0;
    auto al = [&](size_t bytes) { o += (bytes + 255) & ~(size_t)255; };
    al(24 * 32 * 16 * sizeof(unsigned)); // flags
    al((size_t)2 * NB * HCAT * 2);      // hbuf (bf16)
    al((size_t)NB * HCAT * 4);          // cbuf (fp32)
    al(rows * HCAT * 2);                // hs chunk
    al(rows * 256 * 4);                 // z chunk
    al(rows * 2048 * 2);                // gx0 chunk
    al(rows * 1024 * 2);                // gx1 chunk
    al(rows * 1024 * 2);                // gx2 chunk
    if (o <= ws_size) { TC = tc; break; }
  }
  if (TC == 0) {
    k_fill<<<dim3((out_size + 255) / 256), dim3(256), 0, stream>>>(out, out_size, -8888.f);
    return;
  }
  const int tcShift = __builtin_ctz(TC);
  const size_t rows = (size_t)NB * TC;

  char* ws = (char*)d_ws;
  size_t off = 0;
  auto alloc = [&](size_t bytes) -> void* {
    void* p = ws + off;
    off += (bytes + 255) & ~(size_t)255;
    return p;
  };
  unsigned* bar  = (unsigned*)alloc(24 * 32 * 16 * sizeof(unsigned));
  ushort_t* hbuf = (ushort_t*)alloc((size_t)2 * NB * HCAT * 2);
  float* cbuf    = (float*)alloc((size_t)NB * HCAT * 4);
  size_t staticEnd = off;
  ushort_t* hs   = (ushort_t*)alloc(rows * HCAT * 2);
  float* z       = (float*)alloc(rows * 256 * 4);
  ushort_t* gx0  = (ushort_t*)alloc(rows * 2048 * 2);
  ushort_t* gx1  = (ushort_t*)alloc(rows * 1024 * 2);
  ushort_t* gx2  = (ushort_t*)alloc(rows * 1024 * 2);

  // zero flags + hbuf + cbuf (h0 = c0 = 0)
  hipMemsetAsync(ws, 0, staticEnd, stream);

  dim3 blk(256);
  const int rb = (int)(rows / 64);   // row-blocks per chunk
  for (int t0 = 0; t0 < NT; t0 += TC) {
    k_gx_mfma<<<dim3(rb, 2048 / 64), blk, 0, stream>>>(x0, Wih0, bih0, bhh0, gx0, 300, 2048, t0, tcShift);
    k_gx_mfma<<<dim3(rb, 1024 / 64), blk, 0, stream>>>(x1, Wih1, bih1, bhh1, gx1, 74, 1024, t0, tcShift);
    k_gx_mfma<<<dim3(rb, 1024 / 64), blk, 0, stream>>>(x2, Wih2, bih2, bhh2, gx2, 35, 1024, t0, tcShift);

    k_lstm<<<dim3(256), blk, 0, stream>>>(Whh0, Whh1, Whh2,
                                          gx0, gx1, gx2,
                                          hbuf, cbuf, hs, bar, t0, TC);

    k_fc1_mfma<<<dim3(rb, 256 / 64), blk, 0, stream>>>(hs, W1, b1, z);
    k_fc2<<<dim3((int)(rows / 4)), blk, 0, stream>>>(z, W2, b2, out, t0, tcShift);
  }
}

// Round 9
// 1509.095 us; speedup vs baseline: 2.3648x; 1.6878x over previous
//
#include <hip/hip_runtime.h>
#include <hip/hip_bf16.h>
#include <math.h>

typedef __hip_bfloat16 bf16;
typedef unsigned short ushort_t;
typedef unsigned long long ull_t;
typedef __attribute__((ext_vector_type(8))) short short8;
typedef __attribute__((ext_vector_type(4))) float f32x4;

constexpr int NB = 128;      // batch
constexpr int NT = 256;      // time
constexpr int HCAT = 1024;   // 512+256+256
// padded K for bf16 GEMM operands (multiples of 64)
constexpr int KP0 = 320;     // 300
constexpr int KP1 = 128;     // 74
constexpr int KP2 = 64;      // 35

__device__ inline float bf2f(ushort_t u) {
  union { unsigned i; float f; } x; x.i = (unsigned)u << 16; return x.f;
}
__device__ inline ushort_t f2bf(float f) {
  bf16 b = __float2bfloat16(f);
  return *reinterpret_cast<ushort_t*>(&b);
}

// ---------------------------------------------------------------------------
// weight convert: fp32 [R][K] -> bf16 [R][KP], zero-padded
// ---------------------------------------------------------------------------
__global__ __launch_bounds__(256) void k_cvt_w(
    const float* __restrict__ in, ushort_t* __restrict__ out, int R, int K, int KP)
{
  int i = blockIdx.x * 256 + threadIdx.x;
  if (i >= R * KP) return;
  int r = i / KP, k = i - r * KP;
  out[i] = (k < K) ? f2bf(in[(size_t)r * K + k]) : (ushort_t)0;
}

// ---------------------------------------------------------------------------
// x convert: fp32 x[B][NT][d] -> bf16 [rows][KP] (row = b*TC+tl), zero-padded
// ---------------------------------------------------------------------------
__global__ __launch_bounds__(256) void k_cvt_x(
    const float* __restrict__ x, ushort_t* __restrict__ out,
    int d, int KP, int t0, int tcShift, int total)
{
  int i = blockIdx.x * 256 + threadIdx.x;
  if (i >= total) return;
  int row = i / KP, k = i - row * KP;
  int b = row >> tcShift, tl = row & ((1 << tcShift) - 1);
  out[i] = (k < d) ? f2bf(x[((size_t)b * NT + t0 + tl) * d + k]) : (ushort_t)0;
}

// ---------------------------------------------------------------------------
// Generic bf16 B^T GEMM: C[M][ldc](cols col0..) = A[M][KP] @ B[N][KP]^T
// 64x64 tile / block, BK=64, double-buffered LDS, ONE barrier per K-chunk,
// register-prefetched short8 staging (no cvt in loop).
// mode 0: out bf16, bias = bias0[col]+bias1[col]   (gx)
// mode 1: out fp32, relu(acc + bias0[col])         (fc1)
// ---------------------------------------------------------------------------
__global__ __launch_bounds__(256) void k_gemm(
    const ushort_t* __restrict__ A, const ushort_t* __restrict__ B, int KP,
    const float* __restrict__ bias0, const float* __restrict__ bias1,
    ushort_t* __restrict__ outb, float* __restrict__ outf, int ldc, int mode)
{
  __shared__ ushort_t As[2][64][72];
  __shared__ ushort_t Bs[2][64][72];
  const int row0 = blockIdx.x * 64;
  const int col0 = blockIdx.y * 64;
  const int tid  = threadIdx.x;
  const int lane = tid & 63;
  const int w    = tid >> 6;
  const int n    = lane & 15;
  const int quad = lane >> 4;
  const int sr = tid >> 2;           // staging row 0..63
  const int sc = (tid & 3) * 16;     // staging col (elems)

  const ushort_t* arow = A + (size_t)(row0 + sr) * KP + sc;
  const ushort_t* brow = B + (size_t)(col0 + sr) * KP + sc;

  // prologue: chunk 0 into buffer 0
  short8 ra0 = *reinterpret_cast<const short8*>(arow);
  short8 ra1 = *reinterpret_cast<const short8*>(arow + 8);
  short8 rb0 = *reinterpret_cast<const short8*>(brow);
  short8 rb1 = *reinterpret_cast<const short8*>(brow + 8);
  *reinterpret_cast<short8*>(&As[0][sr][sc])     = ra0;
  *reinterpret_cast<short8*>(&As[0][sr][sc + 8]) = ra1;
  *reinterpret_cast<short8*>(&Bs[0][sr][sc])     = rb0;
  *reinterpret_cast<short8*>(&Bs[0][sr][sc + 8]) = rb1;

  f32x4 acc[4] = {{0,0,0,0},{0,0,0,0},{0,0,0,0},{0,0,0,0}};
  const int nch = KP >> 6;
  for (int ch = 0; ch < nch; ++ch) {
    __syncthreads();
    const int cur = ch & 1;
    if (ch + 1 < nch) {
      const ushort_t* an = arow + (ch + 1) * 64;
      const ushort_t* bn = brow + (ch + 1) * 64;
      ra0 = *reinterpret_cast<const short8*>(an);
      ra1 = *reinterpret_cast<const short8*>(an + 8);
      rb0 = *reinterpret_cast<const short8*>(bn);
      rb1 = *reinterpret_cast<const short8*>(bn + 8);
    }
#pragma unroll
    for (int kc = 0; kc < 2; ++kc) {
      short8 bfr = *reinterpret_cast<const short8*>(&Bs[cur][w * 16 + n][quad * 8 + kc * 32]);
#pragma unroll
      for (int mt = 0; mt < 4; ++mt) {
        short8 afr = *reinterpret_cast<const short8*>(&As[cur][mt * 16 + n][quad * 8 + kc * 32]);
        acc[mt] = __builtin_amdgcn_mfma_f32_16x16x32_bf16(afr, bfr, acc[mt], 0, 0, 0);
      }
    }
    if (ch + 1 < nch) {
      const int nxt = 1 - cur;
      *reinterpret_cast<short8*>(&As[nxt][sr][sc])     = ra0;
      *reinterpret_cast<short8*>(&As[nxt][sr][sc + 8]) = ra1;
      *reinterpret_cast<short8*>(&Bs[nxt][sr][sc])     = rb0;
      *reinterpret_cast<short8*>(&Bs[nxt][sr][sc + 8]) = rb1;
    }
  }

  const int col = col0 + w * 16 + n;
  if (mode == 0) {
    const float bsum = bias0[col] + bias1[col];
#pragma unroll
    for (int mt = 0; mt < 4; ++mt)
#pragma unroll
      for (int r = 0; r < 4; ++r) {
        int row = row0 + mt * 16 + quad * 4 + r;
        outb[(size_t)row * ldc + col] = f2bf(acc[mt][r] + bsum);
      }
  } else {
    const float bsum = bias0[col];
#pragma unroll
    for (int mt = 0; mt < 4; ++mt)
#pragma unroll
      for (int r = 0; r < 4; ++r) {
        int row = row0 + mt * 16 + quad * 4 + r;
        outf[(size_t)row * ldc + col] = fmaxf(acc[mt][r] + bsum, 0.f);
      }
  }
}

// ---------------------------------------------------------------------------
// fc2 + log_softmax: one wave per chunk row; map chunk row -> global (b,t)
// ---------------------------------------------------------------------------
__global__ __launch_bounds__(256) void k_fc2(
    const float* __restrict__ Z, const float* __restrict__ W2,
    const float* __restrict__ b2, float* __restrict__ out, int t0, int tcShift)
{
  const int wave = threadIdx.x >> 6;
  const int lane = threadIdx.x & 63;
  const int bt = blockIdx.x * 4 + wave;
  const float* z = Z + (size_t)bt * 256;
  float zv[4];
#pragma unroll
  for (int j = 0; j < 4; ++j) zv[j] = z[lane + 64 * j];
  float lg[7];
#pragma unroll
  for (int o = 0; o < 7; ++o) {
    float a = 0.f;
#pragma unroll
    for (int j = 0; j < 4; ++j) a += zv[j] * W2[o * 256 + lane + 64 * j];
#pragma unroll
    for (int off = 32; off > 0; off >>= 1) a += __shfl_down(a, off, 64);
    lg[o] = a;   // valid on lane 0
  }
  if (lane == 0) {
    const int b = bt >> tcShift;
    const int tl = bt & ((1 << tcShift) - 1);
    float* op = out + ((size_t)b * NT + t0 + tl) * 7;
    float lo[7];
    float m = -1e30f;
#pragma unroll
    for (int o = 0; o < 7; ++o) { lo[o] = lg[o] + b2[o]; m = fmaxf(m, lo[o]); }
    float s = 0.f;
#pragma unroll
    for (int o = 0; o < 7; ++o) s += expf(lo[o] - m);
    float lse = m + logf(s);
#pragma unroll
    for (int o = 0; o < 7; ++o) op[o] = lo[o] - lse;
  }
}

// ---------------------------------------------------------------------------
// Recurrent kernel (unchanged from R8): 32 units/block, LDS-staged h,
// per-producer flag words + vectorized poll, relaxed agent-atomic h exchange,
// hs stores / gx prefetch off the critical path.
// ---------------------------------------------------------------------------
template<int HL>
__device__ void lstm_body(const float* __restrict__ Whh,
                          const ushort_t* __restrict__ gx,   // bf16 bits, [NB][TC][4*HL]
                          ushort_t* __restrict__ hbuf,       // bf16 [2][NB][HCAT]
                          float* __restrict__ cbuf,          // fp32 [NB][HCAT]
                          ushort_t* __restrict__ hs,         // bf16 [NB][TC][HCAT]
                          ushort_t* htile,                   // LDS [16][HL+8]
                          float (*gbuf)[16][34],             // LDS gate tiles
                          unsigned* flags, int myblk, int nblk,
                          int g, int u0, int hoff, int t0, int TC)
{
  constexpr int KC  = HL / 32;
  constexpr int LHP = HL + 8;          // padded LDS row, bf16 units
  const int tid  = threadIdx.x;
  const int lane = tid & 63;
  const int wgate = tid >> 6;          // wave index == gate (i,f,g,o)
  const int n    = lane & 15;
  const int quad = lane >> 4;

  short8 wfrag[2][KC];
#pragma unroll
  for (int tau = 0; tau < 2; ++tau) {
    const float* wrow = Whh + ((size_t)wgate * HL + u0 + 16 * tau + n) * HL + quad * 8;
#pragma unroll
    for (int kc = 0; kc < KC; ++kc) {
      short8 f;
#pragma unroll
      for (int j = 0; j < 8; ++j) f[j] = (short)f2bf(wrow[kc * 32 + j]);
      wfrag[tau][kc] = f;
    }
  }

  const int u  = tid & 31;
  const int bh = tid >> 5;             // 0..7
  const int bb0 = g * 16 + bh;
  const int bb1 = bb0 + 8;
  const int hcol = hoff + u0 + u;
  float c0 = cbuf[(size_t)bb0 * HCAT + hcol];
  float c1 = cbuf[(size_t)bb1 * HCAT + hcol];

  const int srow = wgate * 4 + (lane >> 4);   // 0..15
  const int scol = lane & 15;

  unsigned* myflagp = flags + (lane < nblk ? lane : 0) * 16;

  const size_t G4 = (size_t)(4 * HL);
  float gxv0[4], gxv1[4];
#pragma unroll
  for (int q = 0; q < 4; ++q) {
    gxv0[q] = bf2f(gx[((size_t)bb0 * TC) * G4 + (size_t)q * HL + u0 + u]);
    gxv1[q] = bf2f(gx[((size_t)bb1 * TC) * G4 + (size_t)q * HL + u0 + u]);
  }

  for (int t = 0; t < TC; ++t) {
    const unsigned target = (unsigned)(t0 + t);
    while (true) {
      unsigned v = __hip_atomic_load(myflagp, __ATOMIC_RELAXED, __HIP_MEMORY_SCOPE_AGENT);
      if (__all(v >= target)) break;
      __builtin_amdgcn_s_sleep(1);
    }

    {
      const ushort_t* src =
          hbuf + ((size_t)(t & 1) * NB + g * 16 + srow) * HCAT + hoff;
#pragma unroll
      for (int it = 0; it < HL / 64; ++it) {
        int col = scol * 4 + it * 64;
        ull_t v = __hip_atomic_load(
            reinterpret_cast<const ull_t*>(src + col),
            __ATOMIC_RELAXED, __HIP_MEMORY_SCOPE_AGENT);
        *reinterpret_cast<ull_t*>(htile + srow * LHP + col) = v;
      }
    }
    __syncthreads();

    f32x4 acc0 = {0.f, 0.f, 0.f, 0.f};
    f32x4 acc1 = {0.f, 0.f, 0.f, 0.f};
#pragma unroll
    for (int kc = 0; kc < KC; ++kc) {
      short8 a = *reinterpret_cast<const short8*>(htile + n * LHP + quad * 8 + kc * 32);
      acc0 = __builtin_amdgcn_mfma_f32_16x16x32_bf16(a, wfrag[0][kc], acc0, 0, 0, 0);
      acc1 = __builtin_amdgcn_mfma_f32_16x16x32_bf16(a, wfrag[1][kc], acc1, 0, 0, 0);
    }
#pragma unroll
    for (int r = 0; r < 4; ++r) {
      gbuf[wgate][quad * 4 + r][n]      = acc0[r];
      gbuf[wgate][quad * 4 + r][16 + n] = acc1[r];
    }
    __syncthreads();

    float pi0 = gbuf[0][bh][u] + gxv0[0];
    float pf0 = gbuf[1][bh][u] + gxv0[1];
    float pg0 = gbuf[2][bh][u] + gxv0[2];
    float po0 = gbuf[3][bh][u] + gxv0[3];
    float pi1 = gbuf[0][bh + 8][u] + gxv1[0];
    float pf1 = gbuf[1][bh + 8][u] + gxv1[1];
    float pg1 = gbuf[2][bh + 8][u] + gxv1[2];
    float po1 = gbuf[3][bh + 8][u] + gxv1[3];

    float si0 = 1.f / (1.f + expf(-pi0));
    float sf0 = 1.f / (1.f + expf(-pf0));
    float so0 = 1.f / (1.f + expf(-po0));
    float tg0 = tanhf(pg0);
    c0 = sf0 * c0 + si0 * tg0;
    float h0 = so0 * tanhf(c0);
    float si1 = 1.f / (1.f + expf(-pi1));
    float sf1 = 1.f / (1.f + expf(-pf1));
    float so1 = 1.f / (1.f + expf(-po1));
    float tg1 = tanhf(pg1);
    c1 = sf1 * c1 + si1 * tg1;
    float h1 = so1 * tanhf(c1);

    ushort_t hb0 = f2bf(h0), hb1 = f2bf(h1);
    unsigned nb0 = (unsigned)(ushort_t)__shfl_down((int)hb0, 1, 64);
    unsigned nb1 = (unsigned)(ushort_t)__shfl_down((int)hb1, 1, 64);
    if ((u & 1) == 0) {
      ushort_t* nxt = hbuf + (size_t)((t + 1) & 1) * NB * HCAT;
      unsigned* d0 = reinterpret_cast<unsigned*>(nxt + (size_t)bb0 * HCAT) + (hcol >> 1);
      unsigned* d1 = reinterpret_cast<unsigned*>(nxt + (size_t)bb1 * HCAT) + (hcol >> 1);
      __hip_atomic_store(d0, (unsigned)hb0 | (nb0 << 16), __ATOMIC_RELAXED, __HIP_MEMORY_SCOPE_AGENT);
      __hip_atomic_store(d1, (unsigned)hb1 | (nb1 << 16), __ATOMIC_RELAXED, __HIP_MEMORY_SCOPE_AGENT);
    }

    __syncthreads();
    if (tid == 0) {
      __hip_atomic_store(flags + myblk * 16, (unsigned)(t0 + t + 1),
                         __ATOMIC_RELAXED, __HIP_MEMORY_SCOPE_AGENT);
    }

    hs[((size_t)bb0 * TC + t) * HCAT + hcol] = hb0;
    hs[((size_t)bb1 * TC + t) * HCAT + hcol] = hb1;
    if (t + 1 < TC) {
#pragma unroll
      for (int q = 0; q < 4; ++q) {
        gxv0[q] = bf2f(gx[((size_t)bb0 * TC + t + 1) * G4 + (size_t)q * HL + u0 + u]);
        gxv1[q] = bf2f(gx[((size_t)bb1 * TC + t + 1) * G4 + (size_t)q * HL + u0 + u]);
      }
    }
  }
  cbuf[(size_t)bb0 * HCAT + hcol] = c0;
  cbuf[(size_t)bb1 * HCAT + hcol] = c1;
}

__global__ __launch_bounds__(256, 1) void k_lstm(
    const float* __restrict__ Whh0, const float* __restrict__ Whh1,
    const float* __restrict__ Whh2,
    const ushort_t* __restrict__ gx0, const ushort_t* __restrict__ gx1,
    const ushort_t* __restrict__ gx2,
    ushort_t* __restrict__ hbuf, float* __restrict__ cbuf,
    ushort_t* __restrict__ hs,
    unsigned* __restrict__ bar,
    int t0, int TC)
{
  __shared__ ushort_t htile[16 * 520];
  __shared__ float gbuf[4][16][34];
  const int g    = blockIdx.x & 7;
  const int rank = blockIdx.x >> 3;        // 0..31
  if (rank < 16) {
    lstm_body<512>(Whh0, gx0, hbuf, cbuf, hs, htile, gbuf,
                   bar + (g * 3 + 0) * 32 * 16, rank, 16,
                   g, rank * 32, 0, t0, TC);
  } else if (rank < 24) {
    lstm_body<256>(Whh1, gx1, hbuf, cbuf, hs, htile, gbuf,
                   bar + (g * 3 + 1) * 32 * 16, rank - 16, 8,
                   g, (rank - 16) * 32, 512, t0, TC);
  } else {
    lstm_body<256>(Whh2, gx2, hbuf, cbuf, hs, htile, gbuf,
                   bar + (g * 3 + 2) * 32 * 16, rank - 24, 8,
                   g, (rank - 24) * 32, 768, t0, TC);
  }
}

// fallback if workspace is too small: distinctive sentinel
__global__ void k_fill(float* __restrict__ out, int n, float v) {
  int i = blockIdx.x * 256 + threadIdx.x;
  if (i < n) out[i] = v;
}

extern "C" void kernel_launch(void* const* d_in, const int* in_sizes, int n_in,
                              void* d_out, int out_size, void* d_ws, size_t ws_size,
                              hipStream_t stream) {
  (void)in_sizes; (void)n_in;
  const float* x0  = (const float*)d_in[0];
  const float* x1  = (const float*)d_in[1];
  const float* x2  = (const float*)d_in[2];
  const float* Wih0 = (const float*)d_in[3];
  const float* Whh0 = (const float*)d_in[4];
  const float* bih0 = (const float*)d_in[5];
  const float* bhh0 = (const float*)d_in[6];
  const float* Wih1 = (const float*)d_in[7];
  const float* Whh1 = (const float*)d_in[8];
  const float* bih1 = (const float*)d_in[9];
  const float* bhh1 = (const float*)d_in[10];
  const float* Wih2 = (const float*)d_in[11];
  const float* Whh2 = (const float*)d_in[12];
  const float* bih2 = (const float*)d_in[13];
  const float* bhh2 = (const float*)d_in[14];
  const float* W1 = (const float*)d_in[15];
  const float* b1 = (const float*)d_in[16];
  const float* W2 = (const float*)d_in[17];
  const float* b2 = (const float*)d_in[18];
  float* out = (float*)d_out;

  // static (TC-independent) sizes
  const size_t szFlags = 24 * 32 * 16 * sizeof(unsigned);
  const size_t szHbuf  = (size_t)2 * NB * HCAT * 2;
  const size_t szCbuf  = (size_t)NB * HCAT * 4;
  const size_t szWb0   = (size_t)2048 * KP0 * 2;
  const size_t szWb1   = (size_t)1024 * KP1 * 2;
  const size_t szWb2   = (size_t)1024 * KP2 * 2;
  const size_t szW1b   = (size_t)256 * 1024 * 2;

  // pick largest even chunk TC that fits in ws
  const int cands[6] = {256, 128, 64, 32, 16, 8};
  int TC = 0;
  for (int ci = 0; ci < 6; ++ci) {
    int tc = cands[ci];
    size_t rows = (size_t)NB * tc;
    size_t o = 0;
    auto al = [&](size_t bytes) { o += (bytes + 255) & ~(size_t)255; };
    al(szFlags); al(szHbuf); al(szCbuf);
    al(szWb0); al(szWb1); al(szWb2); al(szW1b);
    al(rows * HCAT * 2);                // hs chunk
    al(rows * 256 * 4);                 // z chunk
    al(rows * 2048 * 2);                // gx0 chunk
    al(rows * 1024 * 2);                // gx1 chunk
    al(rows * 1024 * 2);                // gx2 chunk
    al(rows * KP0 * 2);                 // xb0
    al(rows * KP1 * 2);                 // xb1
    al(rows * KP2 * 2);                 // xb2
    if (o <= ws_size) { TC = tc; break; }
  }
  if (TC == 0) {
    k_fill<<<dim3((out_size + 255) / 256), dim3(256), 0, stream>>>(out, out_size, -8888.f);
    return;
  }
  const int tcShift = __builtin_ctz(TC);
  const size_t rows = (size_t)NB * TC;

  char* ws = (char*)d_ws;
  size_t off = 0;
  auto alloc = [&](size_t bytes) -> void* {
    void* p = ws + off;
    off += (bytes + 255) & ~(size_t)255;
    return p;
  };
  unsigned* bar  = (unsigned*)alloc(szFlags);
  ushort_t* hbuf = (ushort_t*)alloc(szHbuf);
  float* cbuf    = (float*)alloc(szCbuf);
  size_t staticEnd = off;
  ushort_t* wb0  = (ushort_t*)alloc(szWb0);
  ushort_t* wb1  = (ushort_t*)alloc(szWb1);
  ushort_t* wb2  = (ushort_t*)alloc(szWb2);
  ushort_t* w1b  = (ushort_t*)alloc(szW1b);
  ushort_t* hs   = (ushort_t*)alloc(rows * HCAT * 2);
  float* z       = (float*)alloc(rows * 256 * 4);
  ushort_t* gx0  = (ushort_t*)alloc(rows * 2048 * 2);
  ushort_t* gx1  = (ushort_t*)alloc(rows * 1024 * 2);
  ushort_t* gx2  = (ushort_t*)alloc(rows * 1024 * 2);
  ushort_t* xb0  = (ushort_t*)alloc(rows * KP0 * 2);
  ushort_t* xb1  = (ushort_t*)alloc(rows * KP1 * 2);
  ushort_t* xb2  = (ushort_t*)alloc(rows * KP2 * 2);

  // zero flags + hbuf + cbuf (h0 = c0 = 0)
  hipMemsetAsync(ws, 0, staticEnd, stream);

  dim3 blk(256);
  // weight conversion (once per call)
  k_cvt_w<<<dim3((2048 * KP0 + 255) / 256), blk, 0, stream>>>(Wih0, wb0, 2048, 300, KP0);
  k_cvt_w<<<dim3((1024 * KP1 + 255) / 256), blk, 0, stream>>>(Wih1, wb1, 1024, 74, KP1);
  k_cvt_w<<<dim3((1024 * KP2 + 255) / 256), blk, 0, stream>>>(Wih2, wb2, 1024, 35, KP2);
  k_cvt_w<<<dim3((256 * 1024 + 255) / 256), blk, 0, stream>>>(W1, w1b, 256, 1024, 1024);

  const int rb = (int)(rows / 64);   // row-blocks per chunk
  for (int t0 = 0; t0 < NT; t0 += TC) {
    int tot0 = (int)(rows * KP0), tot1 = (int)(rows * KP1), tot2 = (int)(rows * KP2);
    k_cvt_x<<<dim3((tot0 + 255) / 256), blk, 0, stream>>>(x0, xb0, 300, KP0, t0, tcShift, tot0);
    k_cvt_x<<<dim3((tot1 + 255) / 256), blk, 0, stream>>>(x1, xb1, 74, KP1, t0, tcShift, tot1);
    k_cvt_x<<<dim3((tot2 + 255) / 256), blk, 0, stream>>>(x2, xb2, 35, KP2, t0, tcShift, tot2);

    k_gemm<<<dim3(rb, 2048 / 64), blk, 0, stream>>>(xb0, wb0, KP0, bih0, bhh0, gx0, nullptr, 2048, 0);
    k_gemm<<<dim3(rb, 1024 / 64), blk, 0, stream>>>(xb1, wb1, KP1, bih1, bhh1, gx1, nullptr, 1024, 0);
    k_gemm<<<dim3(rb, 1024 / 64), blk, 0, stream>>>(xb2, wb2, KP2, bih2, bhh2, gx2, nullptr, 1024, 0);

    k_lstm<<<dim3(256), blk, 0, stream>>>(Whh0, Whh1, Whh2,
                                          gx0, gx1, gx2,
                                          hbuf, cbuf, hs, bar, t0, TC);

    k_gemm<<<dim3(rb, 256 / 64), blk, 0, stream>>>(hs, w1b, 1024, b1, nullptr, nullptr, z, 256, 1);
    k_fc2<<<dim3((int)(rows / 4)), blk, 0, stream>>>(z, W2, b2, out, t0, tcShift);
  }
}

// Round 10
// 1413.683 us; speedup vs baseline: 2.5244x; 1.0675x over previous
//
#include <hip/hip_runtime.h>
#include <hip/hip_bf16.h>
#include <math.h>

typedef __hip_bfloat16 bf16;
typedef unsigned short ushort_t;
typedef unsigned long long ull_t;
typedef __attribute__((ext_vector_type(8))) short short8;
typedef __attribute__((ext_vector_type(4))) float f32x4;

constexpr int NB = 128;      // batch
constexpr int NT = 256;      // time
constexpr int HCAT = 1024;   // 512+256+256
// padded K for bf16 GEMM operands (multiples of 64)
constexpr int KP0 = 320;     // 300
constexpr int KP1 = 128;     // 74
constexpr int KP2 = 64;      // 35

__device__ inline float bf2f(ushort_t u) {
  union { unsigned i; float f; } x; x.i = (unsigned)u << 16; return x.f;
}
__device__ inline ushort_t f2bf(float f) {
  bf16 b = __float2bfloat16(f);
  return *reinterpret_cast<ushort_t*>(&b);
}
// fast sigmoid/tanh via v_exp + v_rcp; saturate correctly at +-inf, no NaN.
__device__ inline float fsig(float x) {
  return __builtin_amdgcn_rcpf(1.f + __expf(-x));
}
__device__ inline float ftanh(float x) {
  return 2.f * __builtin_amdgcn_rcpf(1.f + __expf(-2.f * x)) - 1.f;
}

// ---------------------------------------------------------------------------
// weight convert: fp32 [R][K] -> bf16 [R][KP], zero-padded
// ---------------------------------------------------------------------------
__global__ __launch_bounds__(256) void k_cvt_w(
    const float* __restrict__ in, ushort_t* __restrict__ out, int R, int K, int KP)
{
  int i = blockIdx.x * 256 + threadIdx.x;
  if (i >= R * KP) return;
  int r = i / KP, k = i - r * KP;
  out[i] = (k < K) ? f2bf(in[(size_t)r * K + k]) : (ushort_t)0;
}

// ---------------------------------------------------------------------------
// x convert: fp32 x[B][NT][d] -> bf16 [rows][KP] (row = b*TC+tl), zero-padded
// ---------------------------------------------------------------------------
__global__ __launch_bounds__(256) void k_cvt_x(
    const float* __restrict__ x, ushort_t* __restrict__ out,
    int d, int KP, int t0, int tcShift, int total)
{
  int i = blockIdx.x * 256 + threadIdx.x;
  if (i >= total) return;
  int row = i / KP, k = i - row * KP;
  int b = row >> tcShift, tl = row & ((1 << tcShift) - 1);
  out[i] = (k < d) ? f2bf(x[((size_t)b * NT + t0 + tl) * d + k]) : (ushort_t)0;
}

// ---------------------------------------------------------------------------
// Generic bf16 B^T GEMM (R9-proven): 64x64 tile, BK=64, dbuf LDS, 1 barrier
// per chunk. mode 0: bf16 out + bias0+bias1 (gx). mode 1: fp32 relu (fc1).
// ---------------------------------------------------------------------------
__global__ __launch_bounds__(256) void k_gemm(
    const ushort_t* __restrict__ A, const ushort_t* __restrict__ B, int KP,
    const float* __restrict__ bias0, const float* __restrict__ bias1,
    ushort_t* __restrict__ outb, float* __restrict__ outf, int ldc, int mode)
{
  __shared__ ushort_t As[2][64][72];
  __shared__ ushort_t Bs[2][64][72];
  const int row0 = blockIdx.x * 64;
  const int col0 = blockIdx.y * 64;
  const int tid  = threadIdx.x;
  const int lane = tid & 63;
  const int w    = tid >> 6;
  const int n    = lane & 15;
  const int quad = lane >> 4;
  const int sr = tid >> 2;           // staging row 0..63
  const int sc = (tid & 3) * 16;     // staging col (elems)

  const ushort_t* arow = A + (size_t)(row0 + sr) * KP + sc;
  const ushort_t* brow = B + (size_t)(col0 + sr) * KP + sc;

  short8 ra0 = *reinterpret_cast<const short8*>(arow);
  short8 ra1 = *reinterpret_cast<const short8*>(arow + 8);
  short8 rb0 = *reinterpret_cast<const short8*>(brow);
  short8 rb1 = *reinterpret_cast<const short8*>(brow + 8);
  *reinterpret_cast<short8*>(&As[0][sr][sc])     = ra0;
  *reinterpret_cast<short8*>(&As[0][sr][sc + 8]) = ra1;
  *reinterpret_cast<short8*>(&Bs[0][sr][sc])     = rb0;
  *reinterpret_cast<short8*>(&Bs[0][sr][sc + 8]) = rb1;

  f32x4 acc[4] = {{0,0,0,0},{0,0,0,0},{0,0,0,0},{0,0,0,0}};
  const int nch = KP >> 6;
  for (int ch = 0; ch < nch; ++ch) {
    __syncthreads();
    const int cur = ch & 1;
    if (ch + 1 < nch) {
      const ushort_t* an = arow + (ch + 1) * 64;
      const ushort_t* bn = brow + (ch + 1) * 64;
      ra0 = *reinterpret_cast<const short8*>(an);
      ra1 = *reinterpret_cast<const short8*>(an + 8);
      rb0 = *reinterpret_cast<const short8*>(bn);
      rb1 = *reinterpret_cast<const short8*>(bn + 8);
    }
#pragma unroll
    for (int kc = 0; kc < 2; ++kc) {
      short8 bfr = *reinterpret_cast<const short8*>(&Bs[cur][w * 16 + n][quad * 8 + kc * 32]);
#pragma unroll
      for (int mt = 0; mt < 4; ++mt) {
        short8 afr = *reinterpret_cast<const short8*>(&As[cur][mt * 16 + n][quad * 8 + kc * 32]);
        acc[mt] = __builtin_amdgcn_mfma_f32_16x16x32_bf16(afr, bfr, acc[mt], 0, 0, 0);
      }
    }
    if (ch + 1 < nch) {
      const int nxt = 1 - cur;
      *reinterpret_cast<short8*>(&As[nxt][sr][sc])     = ra0;
      *reinterpret_cast<short8*>(&As[nxt][sr][sc + 8]) = ra1;
      *reinterpret_cast<short8*>(&Bs[nxt][sr][sc])     = rb0;
      *reinterpret_cast<short8*>(&Bs[nxt][sr][sc + 8]) = rb1;
    }
  }

  const int col = col0 + w * 16 + n;
  if (mode == 0) {
    const float bsum = bias0[col] + bias1[col];
#pragma unroll
    for (int mt = 0; mt < 4; ++mt)
#pragma unroll
      for (int r = 0; r < 4; ++r) {
        int row = row0 + mt * 16 + quad * 4 + r;
        outb[(size_t)row * ldc + col] = f2bf(acc[mt][r] + bsum);
      }
  } else {
    const float bsum = bias0[col];
#pragma unroll
    for (int mt = 0; mt < 4; ++mt)
#pragma unroll
      for (int r = 0; r < 4; ++r) {
        int row = row0 + mt * 16 + quad * 4 + r;
        outf[(size_t)row * ldc + col] = fmaxf(acc[mt][r] + bsum, 0.f);
      }
  }
}

// ---------------------------------------------------------------------------
// fc2 + log_softmax: one wave per chunk row; map chunk row -> global (b,t)
// ---------------------------------------------------------------------------
__global__ __launch_bounds__(256) void k_fc2(
    const float* __restrict__ Z, const float* __restrict__ W2,
    const float* __restrict__ b2, float* __restrict__ out, int t0, int tcShift)
{
  const int wave = threadIdx.x >> 6;
  const int lane = threadIdx.x & 63;
  const int bt = blockIdx.x * 4 + wave;
  const float* z = Z + (size_t)bt * 256;
  float zv[4];
#pragma unroll
  for (int j = 0; j < 4; ++j) zv[j] = z[lane + 64 * j];
  float lg[7];
#pragma unroll
  for (int o = 0; o < 7; ++o) {
    float a = 0.f;
#pragma unroll
    for (int j = 0; j < 4; ++j) a += zv[j] * W2[o * 256 + lane + 64 * j];
#pragma unroll
    for (int off = 32; off > 0; off >>= 1) a += __shfl_down(a, off, 64);
    lg[o] = a;   // valid on lane 0
  }
  if (lane == 0) {
    const int b = bt >> tcShift;
    const int tl = bt & ((1 << tcShift) - 1);
    float* op = out + ((size_t)b * NT + t0 + tl) * 7;
    float lo[7];
    float m = -1e30f;
#pragma unroll
    for (int o = 0; o < 7; ++o) { lo[o] = lg[o] + b2[o]; m = fmaxf(m, lo[o]); }
    float s = 0.f;
#pragma unroll
    for (int o = 0; o < 7; ++o) s += expf(lo[o] - m);
    float lse = m + logf(s);
#pragma unroll
    for (int o = 0; o < 7; ++o) op[o] = lo[o] - lse;
  }
}

// ---------------------------------------------------------------------------
// Recurrent kernel R10: as R9 plus poll-traffic collapse:
//  - flags for a (group,layer) packed into ONE 64B line (4B apart): a poll
//    touches 1 LLC line instead of 16 (memory-side cache merges distinct-word
//    stores, no ownership transfer).
//  - only wave 0 polls; __syncthreads() releases the other 3 waves.
//  - fast sigmoid/tanh (v_exp+v_rcp) trims the serial epilogue.
// ---------------------------------------------------------------------------
template<int HL>
__device__ void lstm_body(const float* __restrict__ Whh,
                          const ushort_t* __restrict__ gx,   // bf16 bits, [NB][TC][4*HL]
                          ushort_t* __restrict__ hbuf,       // bf16 [2][NB][HCAT]
                          float* __restrict__ cbuf,          // fp32 [NB][HCAT]
                          ushort_t* __restrict__ hs,         // bf16 [NB][TC][HCAT]
                          ushort_t* htile,                   // LDS [16][HL+8]
                          float (*gbuf)[16][34],             // LDS gate tiles
                          unsigned* flags, int myblk, int nblk,
                          int g, int u0, int hoff, int t0, int TC)
{
  constexpr int KC  = HL / 32;
  constexpr int LHP = HL + 8;          // padded LDS row, bf16 units
  const int tid  = threadIdx.x;
  const int lane = tid & 63;
  const int wgate = tid >> 6;          // wave index == gate (i,f,g,o)
  const int n    = lane & 15;
  const int quad = lane >> 4;

  short8 wfrag[2][KC];
#pragma unroll
  for (int tau = 0; tau < 2; ++tau) {
    const float* wrow = Whh + ((size_t)wgate * HL + u0 + 16 * tau + n) * HL + quad * 8;
#pragma unroll
    for (int kc = 0; kc < KC; ++kc) {
      short8 f;
#pragma unroll
      for (int j = 0; j < 8; ++j) f[j] = (short)f2bf(wrow[kc * 32 + j]);
      wfrag[tau][kc] = f;
    }
  }

  const int u  = tid & 31;
  const int bh = tid >> 5;             // 0..7
  const int bb0 = g * 16 + bh;
  const int bb1 = bb0 + 8;
  const int hcol = hoff + u0 + u;
  float c0 = cbuf[(size_t)bb0 * HCAT + hcol];
  float c1 = cbuf[(size_t)bb1 * HCAT + hcol];

  const int srow = wgate * 4 + (lane >> 4);   // 0..15
  const int scol = lane & 15;

  // packed flag line: flag i at flags[i] (4B apart, one 64B line per set)
  unsigned* myflagp = flags + (lane < nblk ? lane : 0);

  const size_t G4 = (size_t)(4 * HL);
  float gxv0[4], gxv1[4];
#pragma unroll
  for (int q = 0; q < 4; ++q) {
    gxv0[q] = bf2f(gx[((size_t)bb0 * TC) * G4 + (size_t)q * HL + u0 + u]);
    gxv1[q] = bf2f(gx[((size_t)bb1 * TC) * G4 + (size_t)q * HL + u0 + u]);
  }

  for (int t = 0; t < TC; ++t) {
    const unsigned target = (unsigned)(t0 + t);
    if (wgate == 0) {
      while (true) {
        unsigned v = __hip_atomic_load(myflagp, __ATOMIC_RELAXED, __HIP_MEMORY_SCOPE_AGENT);
        if (__all(v >= target)) break;
        __builtin_amdgcn_s_sleep(1);
      }
    }
    __syncthreads();   // release all waves once wave 0 saw h(t) published

    {
      const ushort_t* src =
          hbuf + ((size_t)(t & 1) * NB + g * 16 + srow) * HCAT + hoff;
#pragma unroll
      for (int it = 0; it < HL / 64; ++it) {
        int col = scol * 4 + it * 64;
        ull_t v = __hip_atomic_load(
            reinterpret_cast<const ull_t*>(src + col),
            __ATOMIC_RELAXED, __HIP_MEMORY_SCOPE_AGENT);
        *reinterpret_cast<ull_t*>(htile + srow * LHP + col) = v;
      }
    }
    __syncthreads();

    f32x4 acc0 = {0.f, 0.f, 0.f, 0.f};
    f32x4 acc1 = {0.f, 0.f, 0.f, 0.f};
#pragma unroll
    for (int kc = 0; kc < KC; ++kc) {
      short8 a = *reinterpret_cast<const short8*>(htile + n * LHP + quad * 8 + kc * 32);
      acc0 = __builtin_amdgcn_mfma_f32_16x16x32_bf16(a, wfrag[0][kc], acc0, 0, 0, 0);
      acc1 = __builtin_amdgcn_mfma_f32_16x16x32_bf16(a, wfrag[1][kc], acc1, 0, 0, 0);
    }
#pragma unroll
    for (int r = 0; r < 4; ++r) {
      gbuf[wgate][quad * 4 + r][n]      = acc0[r];
      gbuf[wgate][quad * 4 + r][16 + n] = acc1[r];
    }
    __syncthreads();

    float pi0 = gbuf[0][bh][u] + gxv0[0];
    float pf0 = gbuf[1][bh][u] + gxv0[1];
    float pg0 = gbuf[2][bh][u] + gxv0[2];
    float po0 = gbuf[3][bh][u] + gxv0[3];
    float pi1 = gbuf[0][bh + 8][u] + gxv1[0];
    float pf1 = gbuf[1][bh + 8][u] + gxv1[1];
    float pg1 = gbuf[2][bh + 8][u] + gxv1[2];
    float po1 = gbuf[3][bh + 8][u] + gxv1[3];

    float si0 = fsig(pi0), sf0 = fsig(pf0), so0 = fsig(po0);
    float tg0 = ftanh(pg0);
    c0 = sf0 * c0 + si0 * tg0;
    float h0 = so0 * ftanh(c0);
    float si1 = fsig(pi1), sf1 = fsig(pf1), so1 = fsig(po1);
    float tg1 = ftanh(pg1);
    c1 = sf1 * c1 + si1 * tg1;
    float h1 = so1 * ftanh(c1);

    ushort_t hb0 = f2bf(h0), hb1 = f2bf(h1);
    unsigned nb0 = (unsigned)(ushort_t)__shfl_down((int)hb0, 1, 64);
    unsigned nb1 = (unsigned)(ushort_t)__shfl_down((int)hb1, 1, 64);
    if ((u & 1) == 0) {
      ushort_t* nxt = hbuf + (size_t)((t + 1) & 1) * NB * HCAT;
      unsigned* d0 = reinterpret_cast<unsigned*>(nxt + (size_t)bb0 * HCAT) + (hcol >> 1);
      unsigned* d1 = reinterpret_cast<unsigned*>(nxt + (size_t)bb1 * HCAT) + (hcol >> 1);
      __hip_atomic_store(d0, (unsigned)hb0 | (nb0 << 16), __ATOMIC_RELAXED, __HIP_MEMORY_SCOPE_AGENT);
      __hip_atomic_store(d1, (unsigned)hb1 | (nb1 << 16), __ATOMIC_RELAXED, __HIP_MEMORY_SCOPE_AGENT);
    }

    __syncthreads();   // drain h stores (vmcnt(0) before s_barrier)
    if (tid == 0) {
      __hip_atomic_store(flags + myblk, (unsigned)(t0 + t + 1),
                         __ATOMIC_RELAXED, __HIP_MEMORY_SCOPE_AGENT);
    }

    // off-critical-path: hs stores + gx(t+1) prefetch
    hs[((size_t)bb0 * TC + t) * HCAT + hcol] = hb0;
    hs[((size_t)bb1 * TC + t) * HCAT + hcol] = hb1;
    if (t + 1 < TC) {
#pragma unroll
      for (int q = 0; q < 4; ++q) {
        gxv0[q] = bf2f(gx[((size_t)bb0 * TC + t + 1) * G4 + (size_t)q * HL + u0 + u]);
        gxv1[q] = bf2f(gx[((size_t)bb1 * TC + t + 1) * G4 + (size_t)q * HL + u0 + u]);
      }
    }
  }
  cbuf[(size_t)bb0 * HCAT + hcol] = c0;
  cbuf[(size_t)bb1 * HCAT + hcol] = c1;
}

__global__ __launch_bounds__(256, 1) void k_lstm(
    const float* __restrict__ Whh0, const float* __restrict__ Whh1,
    const float* __restrict__ Whh2,
    const ushort_t* __restrict__ gx0, const ushort_t* __restrict__ gx1,
    const ushort_t* __restrict__ gx2,
    ushort_t* __restrict__ hbuf, float* __restrict__ cbuf,
    ushort_t* __restrict__ hs,
    unsigned* __restrict__ bar,        // flags: [8 groups][3 layers][16 u32 = 64B line]
    int t0, int TC)
{
  __shared__ ushort_t htile[16 * 520];
  __shared__ float gbuf[4][16][34];
  const int g    = blockIdx.x & 7;
  const int rank = blockIdx.x >> 3;        // 0..31
  if (rank < 16) {
    lstm_body<512>(Whh0, gx0, hbuf, cbuf, hs, htile, gbuf,
                   bar + (g * 3 + 0) * 16, rank, 16,
                   g, rank * 32, 0, t0, TC);
  } else if (rank < 24) {
    lstm_body<256>(Whh1, gx1, hbuf, cbuf, hs, htile, gbuf,
                   bar + (g * 3 + 1) * 16, rank - 16, 8,
                   g, (rank - 16) * 32, 512, t0, TC);
  } else {
    lstm_body<256>(Whh2, gx2, hbuf, cbuf, hs, htile, gbuf,
                   bar + (g * 3 + 2) * 16, rank - 24, 8,
                   g, (rank - 24) * 32, 768, t0, TC);
  }
}

// fallback if workspace is too small: distinctive sentinel
__global__ void k_fill(float* __restrict__ out, int n, float v) {
  int i = blockIdx.x * 256 + threadIdx.x;
  if (i < n) out[i] = v;
}

extern "C" void kernel_launch(void* const* d_in, const int* in_sizes, int n_in,
                              void* d_out, int out_size, void* d_ws, size_t ws_size,
                              hipStream_t stream) {
  (void)in_sizes; (void)n_in;
  const float* x0  = (const float*)d_in[0];
  const float* x1  = (const float*)d_in[1];
  const float* x2  = (const float*)d_in[2];
  const float* Wih0 = (const float*)d_in[3];
  const float* Whh0 = (const float*)d_in[4];
  const float* bih0 = (const float*)d_in[5];
  const float* bhh0 = (const float*)d_in[6];
  const float* Wih1 = (const float*)d_in[7];
  const float* Whh1 = (const float*)d_in[8];
  const float* bih1 = (const float*)d_in[9];
  const float* bhh1 = (const float*)d_in[10];
  const float* Wih2 = (const float*)d_in[11];
  const float* Whh2 = (const float*)d_in[12];
  const float* bih2 = (const float*)d_in[13];
  const float* bhh2 = (const float*)d_in[14];
  const float* W1 = (const float*)d_in[15];
  const float* b1 = (const float*)d_in[16];
  const float* W2 = (const float*)d_in[17];
  const float* b2 = (const float*)d_in[18];
  float* out = (float*)d_out;

  const size_t szFlags = 24 * 16 * sizeof(unsigned);
  const size_t szHbuf  = (size_t)2 * NB * HCAT * 2;
  const size_t szCbuf  = (size_t)NB * HCAT * 4;
  const size_t szWb0   = (size_t)2048 * KP0 * 2;
  const size_t szWb1   = (size_t)1024 * KP1 * 2;
  const size_t szWb2   = (size_t)1024 * KP2 * 2;
  const size_t szW1b   = (size_t)256 * 1024 * 2;

  const int cands[6] = {256, 128, 64, 32, 16, 8};
  int TC = 0;
  for (int ci = 0; ci < 6; ++ci) {
    int tc = cands[ci];
    size_t rows = (size_t)NB * tc;
    size_t o = 0;
    auto al = [&](size_t bytes) { o += (bytes + 255) & ~(size_t)255; };
    al(szFlags); al(szHbuf); al(szCbuf);
    al(szWb0); al(szWb1); al(szWb2); al(szW1b);
    al(rows * HCAT * 2);                // hs chunk
    al(rows * 256 * 4);                 // z chunk
    al(rows * 2048 * 2);                // gx0 chunk
    al(rows * 1024 * 2);                // gx1 chunk
    al(rows * 1024 * 2);                // gx2 chunk
    al(rows * KP0 * 2);                 // xb0
    al(rows * KP1 * 2);                 // xb1
    al(rows * KP2 * 2);                 // xb2
    if (o <= ws_size) { TC = tc; break; }
  }
  if (TC == 0) {
    k_fill<<<dim3((out_size + 255) / 256), dim3(256), 0, stream>>>(out, out_size, -8888.f);
    return;
  }
  const int tcShift = __builtin_ctz(TC);
  const size_t rows = (size_t)NB * TC;

  char* ws = (char*)d_ws;
  size_t off = 0;
  auto alloc = [&](size_t bytes) -> void* {
    void* p = ws + off;
    off += (bytes + 255) & ~(size_t)255;
    return p;
  };
  unsigned* bar  = (unsigned*)alloc(szFlags);
  ushort_t* hbuf = (ushort_t*)alloc(szHbuf);
  float* cbuf    = (float*)alloc(szCbuf);
  size_t staticEnd = off;
  ushort_t* wb0  = (ushort_t*)alloc(szWb0);
  ushort_t* wb1  = (ushort_t*)alloc(szWb1);
  ushort_t* wb2  = (ushort_t*)alloc(szWb2);
  ushort_t* w1b  = (ushort_t*)alloc(szW1b);
  ushort_t* hs   = (ushort_t*)alloc(rows * HCAT * 2);
  float* z       = (float*)alloc(rows * 256 * 4);
  ushort_t* gx0  = (ushort_t*)alloc(rows * 2048 * 2);
  ushort_t* gx1  = (ushort_t*)alloc(rows * 1024 * 2);
  ushort_t* gx2  = (ushort_t*)alloc(rows * 1024 * 2);
  ushort_t* xb0  = (ushort_t*)alloc(rows * KP0 * 2);
  ushort_t* xb1  = (ushort_t*)alloc(rows * KP1 * 2);
  ushort_t* xb2  = (ushort_t*)alloc(rows * KP2 * 2);

  hipMemsetAsync(ws, 0, staticEnd, stream);

  dim3 blk(256);
  k_cvt_w<<<dim3((2048 * KP0 + 255) / 256), blk, 0, stream>>>(Wih0, wb0, 2048, 300, KP0);
  k_cvt_w<<<dim3((1024 * KP1 + 255) / 256), blk, 0, stream>>>(Wih1, wb1, 1024, 74, KP1);
  k_cvt_w<<<dim3((1024 * KP2 + 255) / 256), blk, 0, stream>>>(Wih2, wb2, 1024, 35, KP2);
  k_cvt_w<<<dim3((256 * 1024 + 255) / 256), blk, 0, stream>>>(W1, w1b, 256, 1024, 1024);

  const int rb = (int)(rows / 64);   // row-blocks per chunk
  for (int t0 = 0; t0 < NT; t0 += TC) {
    int tot0 = (int)(rows * KP0), tot1 = (int)(rows * KP1), tot2 = (int)(rows * KP2);
    k_cvt_x<<<dim3((tot0 + 255) / 256), blk, 0, stream>>>(x0, xb0, 300, KP0, t0, tcShift, tot0);
    k_cvt_x<<<dim3((tot1 + 255) / 256), blk, 0, stream>>>(x1, xb1, 74, KP1, t0, tcShift, tot1);
    k_cvt_x<<<dim3((tot2 + 255) / 256), blk, 0, stream>>>(x2, xb2, 35, KP2, t0, tcShift, tot2);

    k_gemm<<<dim3(rb, 2048 / 64), blk, 0, stream>>>(xb0, wb0, KP0, bih0, bhh0, gx0, nullptr, 2048, 0);
    k_gemm<<<dim3(rb, 1024 / 64), blk, 0, stream>>>(xb1, wb1, KP1, bih1, bhh1, gx1, nullptr, 1024, 0);
    k_gemm<<<dim3(rb, 1024 / 64), blk, 0, stream>>>(xb2, wb2, KP2, bih2, bhh2, gx2, nullptr, 1024, 0);

    k_lstm<<<dim3(256), blk, 0, stream>>>(Whh0, Whh1, Whh2,
                                          gx0, gx1, gx2,
                                          hbuf, cbuf, hs, bar, t0, TC);

    k_gemm<<<dim3(rb, 256 / 64), blk, 0, stream>>>(hs, w1b, 1024, b1, nullptr, nullptr, z, 256, 1);
    k_fc2<<<dim3((int)(rows / 4)), blk, 0, stream>>>(z, W2, b2, out, t0, tcShift);
  }
}